// Round 1
// baseline (3533.981 us; speedup 1.0000x reference)
//
#include <hip/hip_runtime.h>
#include <math.h>

#define N_NODES 50000
#define N_EDGES 800000

__device__ __forceinline__ float silu_f(float x) {
    return x / (1.0f + __expf(-x));
}

// ---------------------------------------------------------------------------
// Cayley: per layer, M = (A + A^H) + iI ; Q = I - 2i * inv(M)
// In-place complex Gauss-Jordan (no pivoting; M ~ iI + small Hermitian).
// Writes Q transposed: qre_t[k*128+j] = Re Q[j][k], qim_t likewise.
// ---------------------------------------------------------------------------
__global__ __launch_bounds__(1024) void cayley_kernel(const float* __restrict__ A_real,
                                                      const float* __restrict__ A_imag,
                                                      float* __restrict__ qmat) {
    __shared__ float Mre[128 * 128];
    __shared__ float Mim[128 * 128];
    const int L = blockIdx.x;
    const int t = threadIdx.x;
    const float* ar = A_real + L * 16384;
    const float* ai = A_imag + L * 16384;

    for (int q = 0; q < 16; ++q) {
        int idx = t + 1024 * q;
        int i = idx >> 7, j = idx & 127;
        Mre[idx] = ar[idx] + ar[j * 128 + i];
        Mim[idx] = ai[idx] - ai[j * 128 + i] + (i == j ? 1.0f : 0.0f);
    }
    __syncthreads();

    const int i = t >> 3;   // row for elimination (8 threads per row)
    const int l8 = t & 7;

    for (int p = 0; p < 128; ++p) {
        float pr = Mre[p * 128 + p], pi = Mim[p * 128 + p];
        float den = 1.0f / (pr * pr + pi * pi);
        float ir = pr * den, ii = -pi * den;
        __syncthreads();
        // read f for my row (col p untouched by scale phase), scale row p
        float fr = 0.f, fi = 0.f;
        if (i != p) { fr = Mre[i * 128 + p]; fi = Mim[i * 128 + p]; }
        if (t < 128) {
            int j = t;
            if (j == p) { Mre[p * 128 + p] = ir; Mim[p * 128 + p] = ii; }
            else {
                float mr = Mre[p * 128 + j], mi = Mim[p * 128 + j];
                Mre[p * 128 + j] = mr * ir - mi * ii;
                Mim[p * 128 + j] = mr * ii + mi * ir;
            }
        }
        __syncthreads();
        if (i != p) {
            #pragma unroll
            for (int c = 0; c < 16; ++c) {
                int j = l8 + 8 * c;
                if (j == p) {
                    Mre[i * 128 + j] = -(fr * ir - fi * ii);
                    Mim[i * 128 + j] = -(fr * ii + fi * ir);
                } else {
                    float mr = Mre[p * 128 + j], mi = Mim[p * 128 + j];
                    Mre[i * 128 + j] -= fr * mr - fi * mi;
                    Mim[i * 128 + j] -= fr * mi + fi * mr;
                }
            }
        }
        __syncthreads();
    }

    float* qre_t = qmat + L * 32768;
    float* qim_t = qre_t + 16384;
    for (int q = 0; q < 16; ++q) {
        int idx = t + 1024 * q;
        int k = idx >> 7, j = idx & 127;
        // Q[j][k] = delta(j,k) + 2*Im(invM[j][k]) - 2i*Re(invM[j][k])
        qre_t[idx] = (j == k ? 1.0f : 0.0f) + 2.0f * Mim[j * 128 + k];
        qim_t[idx] = -2.0f * Mre[j * 128 + k];
    }
}

// ---------------------------------------------------------------------------
// Fused edge MLP: e=silu([h[row],h[col]]@W1+b1); ef=silu(e@W2+b2)
// writes ef to out, atomicAdd into agg[row].
// 512 threads; 64 edges per tile; thread = (jl in 0..31 -> 4 channels) x
// (eg in 0..15 -> 4 edges). W staged in 64x128 LDS slabs.
// ---------------------------------------------------------------------------
__global__ __launch_bounds__(512) void edge_kernel(const float* __restrict__ h,
                                                   const int* __restrict__ ei,
                                                   const float* __restrict__ W_e1,
                                                   const float* __restrict__ b_e1,
                                                   const float* __restrict__ W_e2,
                                                   const float* __restrict__ b_e2,
                                                   float* __restrict__ ef_out,
                                                   float* __restrict__ agg) {
    __shared__ float4 xs4[64 * 64];    // 64 edges x 256 floats   (64 KiB)
    __shared__ float4 slab4[2048];     // 64 x 128 floats         (32 KiB)
    __shared__ float4 et4[64 * 32];    // 64 edges x 128 floats   (32 KiB)
    __shared__ int rows_s[64];

    const int t = threadIdx.x;
    const int jl = t & 31;             // channel group: j = jl*4 .. jl*4+3
    const int eg4 = (t >> 5) * 4;      // first of 4 edges
    const float4 bias1 = ((const float4*)b_e1)[jl];
    const float4 bias2 = ((const float4*)b_e2)[jl];
    const float4* h4 = (const float4*)h;
    const float4* w14 = (const float4*)W_e1;
    const float4* w24 = (const float4*)W_e2;
    const int e_l = t >> 3;
    const int f8 = t & 7;

    for (int tile = blockIdx.x; tile < N_EDGES / 64; tile += gridDim.x) {
        const int e0 = tile * 64;
        // ---- stage x = [h[row], h[col]] for 64 edges ----
        int ri = ei[e0 + e_l];
        int ci = ei[N_EDGES + e0 + e_l];
        if (f8 == 0) rows_s[e_l] = ri;
        #pragma unroll
        for (int q = 0; q < 8; ++q) {
            int u = f8 + 8 * q;
            xs4[e_l * 64 + u] = (u < 32) ? h4[(size_t)ri * 32 + u]
                                         : h4[(size_t)ci * 32 + (u - 32)];
        }

        // ---- GEMM1: 256 -> 128 ----
        float acc[4][4];
        #pragma unroll
        for (int r = 0; r < 4; ++r) { acc[r][0] = acc[r][1] = acc[r][2] = acc[r][3] = 0.f; }
        for (int s = 0; s < 4; ++s) {
            #pragma unroll
            for (int q = 0; q < 4; ++q) slab4[t + 512 * q] = w14[s * 2048 + t + 512 * q];
            __syncthreads();
            #pragma unroll 4
            for (int kk = 0; kk < 16; ++kk) {
                float4 w0 = slab4[(kk * 4 + 0) * 32 + jl];
                float4 w1 = slab4[(kk * 4 + 1) * 32 + jl];
                float4 w2 = slab4[(kk * 4 + 2) * 32 + jl];
                float4 w3 = slab4[(kk * 4 + 3) * 32 + jl];
                #pragma unroll
                for (int r = 0; r < 4; ++r) {
                    float4 x = xs4[(eg4 + r) * 64 + s * 16 + kk];
                    acc[r][0] += x.x * w0.x + x.y * w1.x + x.z * w2.x + x.w * w3.x;
                    acc[r][1] += x.x * w0.y + x.y * w1.y + x.z * w2.y + x.w * w3.y;
                    acc[r][2] += x.x * w0.z + x.y * w1.z + x.z * w2.z + x.w * w3.z;
                    acc[r][3] += x.x * w0.w + x.y * w1.w + x.z * w2.w + x.w * w3.w;
                }
            }
            __syncthreads();
        }
        // ---- bias + silu -> et ----
        #pragma unroll
        for (int r = 0; r < 4; ++r) {
            float4 v;
            v.x = silu_f(acc[r][0] + bias1.x);
            v.y = silu_f(acc[r][1] + bias1.y);
            v.z = silu_f(acc[r][2] + bias1.z);
            v.w = silu_f(acc[r][3] + bias1.w);
            et4[(eg4 + r) * 32 + jl] = v;
        }
        // ---- GEMM2: 128 -> 128 ----
        #pragma unroll
        for (int r = 0; r < 4; ++r) { acc[r][0] = acc[r][1] = acc[r][2] = acc[r][3] = 0.f; }
        for (int s = 0; s < 2; ++s) {
            #pragma unroll
            for (int q = 0; q < 4; ++q) slab4[t + 512 * q] = w24[s * 2048 + t + 512 * q];
            __syncthreads();
            #pragma unroll 4
            for (int kk = 0; kk < 16; ++kk) {
                float4 w0 = slab4[(kk * 4 + 0) * 32 + jl];
                float4 w1 = slab4[(kk * 4 + 1) * 32 + jl];
                float4 w2 = slab4[(kk * 4 + 2) * 32 + jl];
                float4 w3 = slab4[(kk * 4 + 3) * 32 + jl];
                #pragma unroll
                for (int r = 0; r < 4; ++r) {
                    float4 x = et4[(eg4 + r) * 32 + s * 16 + kk];
                    acc[r][0] += x.x * w0.x + x.y * w1.x + x.z * w2.x + x.w * w3.x;
                    acc[r][1] += x.x * w0.y + x.y * w1.y + x.z * w2.y + x.w * w3.y;
                    acc[r][2] += x.x * w0.z + x.y * w1.z + x.z * w2.z + x.w * w3.z;
                    acc[r][3] += x.x * w0.w + x.y * w1.w + x.z * w2.w + x.w * w3.w;
                }
            }
            __syncthreads();
        }
        // ---- bias + silu -> edge_feat out + atomic agg ----
        #pragma unroll
        for (int r = 0; r < 4; ++r) {
            int e = eg4 + r;
            float4 v;
            v.x = silu_f(acc[r][0] + bias2.x);
            v.y = silu_f(acc[r][1] + bias2.y);
            v.z = silu_f(acc[r][2] + bias2.z);
            v.w = silu_f(acc[r][3] + bias2.w);
            *(float4*)(ef_out + (size_t)(e0 + e) * 128 + jl * 4) = v;
            int rw = rows_s[e];
            float* ap = agg + (size_t)rw * 128 + jl * 4;
            atomicAdd(ap + 0, v.x);
            atomicAdd(ap + 1, v.y);
            atomicAdd(ap + 2, v.z);
            atomicAdd(ap + 3, v.w);
        }
        __syncthreads();   // protect rows_s/xs4 restage
    }
}

// ---------------------------------------------------------------------------
// Encode: q = [h, agg] @ W_enc + b_enc ; psi_re = q / ||q||
// ---------------------------------------------------------------------------
__global__ __launch_bounds__(256) void encode_kernel(const float* __restrict__ h,
                                                     const float* __restrict__ agg,
                                                     const float* __restrict__ W_enc,
                                                     const float* __restrict__ b_enc,
                                                     float* __restrict__ psi_re) {
    __shared__ float wl[256 * 128];   // 128 KiB
    __shared__ float xb[16 * 256];    // 16 KiB
    __shared__ float qb[16 * 128];    // 8 KiB
    __shared__ float nrm[16];
    const int t = threadIdx.x;
    const int j = t & 127;
    const int g = t >> 7;
    {
        float4* wl4 = (float4*)wl;
        const float4* we4 = (const float4*)W_enc;
        for (int q = 0; q < 32; ++q) wl4[t + 256 * q] = we4[t + 256 * q];
    }
    const float bj = b_enc[j];
    const float4* h4 = (const float4*)h;
    const float4* a4 = (const float4*)agg;
    float4* xb4 = (float4*)xb;
    __syncthreads();

    for (int tile = blockIdx.x; tile < N_NODES / 16; tile += gridDim.x) {
        const int n0 = tile * 16;
        #pragma unroll
        for (int p = 0; p < 4; ++p) {
            int idx = t + 256 * p;
            int r = idx >> 6, u = idx & 63;
            xb4[idx] = (u < 32) ? h4[(size_t)(n0 + r) * 32 + u]
                                : a4[(size_t)(n0 + r) * 32 + (u - 32)];
        }
        __syncthreads();
        float acc[8] = {0, 0, 0, 0, 0, 0, 0, 0};
        for (int k4 = 0; k4 < 64; ++k4) {
            float w0 = wl[(k4 * 4 + 0) * 128 + j];
            float w1 = wl[(k4 * 4 + 1) * 128 + j];
            float w2 = wl[(k4 * 4 + 2) * 128 + j];
            float w3 = wl[(k4 * 4 + 3) * 128 + j];
            #pragma unroll
            for (int rr = 0; rr < 8; ++rr) {
                float4 x = xb4[(g * 8 + rr) * 64 + k4];
                acc[rr] += x.x * w0 + x.y * w1 + x.z * w2 + x.w * w3;
            }
        }
        #pragma unroll
        for (int rr = 0; rr < 8; ++rr) {
            acc[rr] += bj;
            qb[(g * 8 + rr) * 128 + j] = acc[rr];
        }
        __syncthreads();
        {
            int r2 = t >> 4, l = t & 15;
            float s = 0.f;
            #pragma unroll
            for (int m = 0; m < 8; ++m) { float v = qb[r2 * 128 + l + 16 * m]; s += v * v; }
            s += __shfl_xor(s, 1);
            s += __shfl_xor(s, 2);
            s += __shfl_xor(s, 4);
            s += __shfl_xor(s, 8);
            if (l == 0) nrm[r2] = 1.0f / sqrtf(s + 1e-12f);
        }
        __syncthreads();
        #pragma unroll
        for (int rr = 0; rr < 8; ++rr) {
            psi_re[(size_t)(n0 + g * 8 + rr) * 128 + j] = acc[rr] * nrm[g * 8 + rr];
        }
        __syncthreads();
    }
}

// ---------------------------------------------------------------------------
// Evolve one layer: psi = CNOT( G^{x7}( psi @ Q^T ) )
// ---------------------------------------------------------------------------
template <int LAYER>
__global__ __launch_bounds__(256) void evolve_kernel(float* __restrict__ psi_re,
                                                     float* __restrict__ psi_im,
                                                     const float* __restrict__ qre_t,
                                                     const float* __restrict__ qim_t,
                                                     const float* __restrict__ coeffs) {
    __shared__ float qre_l[16384];   // 64 KiB, [k][j] = Q[j][k]
    __shared__ float qim_l[16384];   // 64 KiB
    __shared__ float2 bufA[8 * 128]; // 8 KiB
    __shared__ float2 bufB[8 * 128]; // 8 KiB
    const int t = threadIdx.x;
    const int j = t & 127;
    const int g = t >> 7;
    {
        float4* d = (float4*)qre_l;
        const float4* s_ = (const float4*)qre_t;
        for (int q = 0; q < 16; ++q) d[t + 256 * q] = s_[t + 256 * q];
        d = (float4*)qim_l;
        s_ = (const float4*)qim_t;
        for (int q = 0; q < 16; ++q) d[t + 256 * q] = s_[t + 256 * q];
    }
    const float tx = coeffs[2 * LAYER + 0] * 0.5f;
    const float ty = coeffs[2 * LAYER + 1] * 0.5f;
    const float cx = cosf(tx), sx = sinf(tx), cy = cosf(ty), sy = sinf(ty);
    // G = RY@RX: G00=cxcy+i sxsy; G01=-cxsy-i sxcy; G10=cxsy-i sxcy; G11=cxcy-i sxsy
    const float G00r = cx * cy, G00i = sx * sy;
    const float G01r = -cx * sy, G01i = -sx * cy;
    const float G10r = cx * sy, G10i = -sx * cy;
    const float G11r = cx * cy, G11i = -sx * sy;
    // CNOT gather source index
    int src = j;
    {
        const int cs[7] = {6, 5, 4, 3, 2, 1, 0};
        const int ts[7] = {0, 6, 5, 4, 3, 2, 1};
        #pragma unroll
        for (int m = 0; m < 7; ++m) {
            int cbit = 1 << (6 - cs[m]);
            int tbit = 1 << (6 - ts[m]);
            if (src & cbit) src ^= tbit;
        }
    }
    __syncthreads();

    for (int tile = blockIdx.x; tile < N_NODES / 8; tile += gridDim.x) {
        const int n0 = tile * 8;
        #pragma unroll
        for (int p = 0; p < 4; ++p) {
            int r = p * 2 + g;
            float re = psi_re[(size_t)(n0 + r) * 128 + j];
            float im = LAYER ? psi_im[(size_t)(n0 + r) * 128 + j] : 0.0f;
            bufA[r * 128 + j] = make_float2(re, im);
        }
        __syncthreads();
        // matmul: out[j] = sum_k row[k] * Q[j][k]
        float arr[4] = {0, 0, 0, 0}, aii[4] = {0, 0, 0, 0};
        for (int k = 0; k < 128; ++k) {
            float qr = qre_l[k * 128 + j];
            float qi = qim_l[k * 128 + j];
            #pragma unroll
            for (int r = 0; r < 4; ++r) {
                float2 x = bufA[(g * 4 + r) * 128 + k];
                arr[r] += x.x * qr;
                aii[r] += x.x * qi;
                if (LAYER) { arr[r] -= x.y * qi; aii[r] += x.y * qr; }
            }
        }
        #pragma unroll
        for (int r = 0; r < 4; ++r) bufB[(g * 4 + r) * 128 + j] = make_float2(arr[r], aii[r]);
        __syncthreads();
        // 7 single-qubit gate stages (commute; any order), ping-pong B<->A
        float2* sb = bufB;
        float2* db = bufA;
        #pragma unroll
        for (int stage = 0; stage < 7; ++stage) {
            const int b = 1 << stage;
            const bool hi = (j & b) != 0;
            const float cor = hi ? G11r : G00r, coi = hi ? G11i : G00i;
            const float cpr = hi ? G10r : G01r, cpi = hi ? G10i : G01i;
            #pragma unroll
            for (int r = 0; r < 4; ++r) {
                int row = g * 4 + r;
                float2 v1 = sb[row * 128 + j];
                float2 v2 = sb[row * 128 + (j ^ b)];
                float nr = cor * v1.x - coi * v1.y + cpr * v2.x - cpi * v2.y;
                float ni = cor * v1.y + coi * v1.x + cpr * v2.y + cpi * v2.x;
                db[row * 128 + j] = make_float2(nr, ni);
            }
            __syncthreads();
            float2* tmp = sb; sb = db; db = tmp;
        }
        // CNOT permutation + store
        #pragma unroll
        for (int r = 0; r < 4; ++r) {
            int row = g * 4 + r;
            float2 v = sb[row * 128 + src];
            psi_re[(size_t)(n0 + row) * 128 + j] = v.x;
            psi_im[(size_t)(n0 + row) * 128 + j] = v.y;
        }
        __syncthreads();
    }
}

// ---------------------------------------------------------------------------
// Decode: out = h + psi_re @ W_dec + b_dec
// ---------------------------------------------------------------------------
__global__ __launch_bounds__(256) void decode_kernel(const float* __restrict__ psi_re,
                                                     const float* __restrict__ h,
                                                     const float* __restrict__ W_dec,
                                                     const float* __restrict__ b_dec,
                                                     float* __restrict__ out) {
    __shared__ float wl[128 * 128];  // 64 KiB
    __shared__ float xb[16 * 128];   // 8 KiB
    const int t = threadIdx.x;
    const int j = t & 127;
    const int g = t >> 7;
    {
        float4* wl4 = (float4*)wl;
        const float4* wd4 = (const float4*)W_dec;
        for (int q = 0; q < 16; ++q) wl4[t + 256 * q] = wd4[t + 256 * q];
    }
    const float bj = b_dec[j];
    const float4* p4 = (const float4*)psi_re;
    float4* xb4 = (float4*)xb;
    __syncthreads();

    for (int tile = blockIdx.x; tile < N_NODES / 16; tile += gridDim.x) {
        const int n0 = tile * 16;
        #pragma unroll
        for (int p = 0; p < 2; ++p) {
            int idx = t + 256 * p;
            int r = idx >> 5, u = idx & 31;
            xb4[idx] = p4[(size_t)(n0 + r) * 32 + u];
        }
        __syncthreads();
        float acc[8] = {0, 0, 0, 0, 0, 0, 0, 0};
        for (int k4 = 0; k4 < 32; ++k4) {
            float w0 = wl[(k4 * 4 + 0) * 128 + j];
            float w1 = wl[(k4 * 4 + 1) * 128 + j];
            float w2 = wl[(k4 * 4 + 2) * 128 + j];
            float w3 = wl[(k4 * 4 + 3) * 128 + j];
            #pragma unroll
            for (int rr = 0; rr < 8; ++rr) {
                float4 x = xb4[(g * 8 + rr) * 32 + k4];
                acc[rr] += x.x * w0 + x.y * w1 + x.z * w2 + x.w * w3;
            }
        }
        #pragma unroll
        for (int rr = 0; rr < 8; ++rr) {
            size_t n = (size_t)(n0 + g * 8 + rr);
            out[n * 128 + j] = h[n * 128 + j] + acc[rr] + bj;
        }
        __syncthreads();
    }
}

// ---------------------------------------------------------------------------
extern "C" void kernel_launch(void* const* d_in, const int* in_sizes, int n_in,
                              void* d_out, int out_size, void* d_ws, size_t ws_size,
                              hipStream_t stream) {
    const float* h      = (const float*)d_in[0];
    const int*   ei     = (const int*)d_in[1];
    const float* W_e1   = (const float*)d_in[2];
    const float* b_e1   = (const float*)d_in[3];
    const float* W_e2   = (const float*)d_in[4];
    const float* b_e2   = (const float*)d_in[5];
    const float* W_enc  = (const float*)d_in[6];
    const float* b_enc  = (const float*)d_in[7];
    const float* coeffs = (const float*)d_in[8];
    const float* A_real = (const float*)d_in[9];
    const float* A_imag = (const float*)d_in[10];
    const float* W_dec  = (const float*)d_in[11];
    const float* b_dec  = (const float*)d_in[12];

    float* out    = (float*)d_out;                 // N*128
    float* ef_out = out + (size_t)N_NODES * 128;   // E*128

    float* ws     = (float*)d_ws;
    float* agg    = ws;                              // 6.4M floats
    float* psi_re = ws + (size_t)N_NODES * 128;      // 6.4M
    float* psi_im = psi_re + (size_t)N_NODES * 128;  // 6.4M
    float* qmat   = psi_im + (size_t)N_NODES * 128;  // 2 * 32768 floats

    hipMemsetAsync(agg, 0, (size_t)N_NODES * 128 * sizeof(float), stream);

    cayley_kernel<<<2, 1024, 0, stream>>>(A_real, A_imag, qmat);

    edge_kernel<<<256, 512, 0, stream>>>(h, ei, W_e1, b_e1, W_e2, b_e2, ef_out, agg);

    encode_kernel<<<256, 256, 0, stream>>>(h, agg, W_enc, b_enc, psi_re);

    evolve_kernel<0><<<256, 256, 0, stream>>>(psi_re, psi_im, qmat, qmat + 16384, coeffs);
    evolve_kernel<1><<<256, 256, 0, stream>>>(psi_re, psi_im, qmat + 32768, qmat + 49152, coeffs);

    decode_kernel<<<512, 256, 0, stream>>>(psi_re, h, W_dec, b_dec, out);
}

// Round 2
// 2666.976 us; speedup vs baseline: 1.3251x; 1.3251x over previous
//
#include <hip/hip_runtime.h>
#include <math.h>

#define N_NODES 50000
#define N_EDGES 800000

typedef __attribute__((ext_vector_type(8))) short bf16x8;
typedef __attribute__((ext_vector_type(4))) short bf16x4v;
typedef __attribute__((ext_vector_type(4))) float f32x4;

__device__ __forceinline__ float silu_f(float x) {
    return x / (1.0f + __expf(-x));
}

__device__ __forceinline__ unsigned short f2bf(float x) {
    union { float f; unsigned u; } v; v.f = x;
    unsigned r = v.u + 0x7FFFu + ((v.u >> 16) & 1u);
    return (unsigned short)(r >> 16);
}

// ---------------------------------------------------------------------------
// Cayley: per layer, M = (A + A^H) + iI ; Q = I - 2i * inv(M)
// Gauss-Jordan, stride padded to 129 (bank-conflict-free), 2 barriers/pivot.
// Writes Q transposed: qre_t[k*128+j] = Re Q[j][k].
// ---------------------------------------------------------------------------
__global__ __launch_bounds__(1024) void cayley_kernel(const float* __restrict__ A_real,
                                                      const float* __restrict__ A_imag,
                                                      float* __restrict__ qmat) {
    __shared__ float Mre[128 * 129];
    __shared__ float Mim[128 * 129];
    const int L = blockIdx.x;
    const int t = threadIdx.x;
    const float* ar = A_real + L * 16384;
    const float* ai = A_imag + L * 16384;

    for (int q = 0; q < 16; ++q) {
        int idx = t + 1024 * q;
        int i = idx >> 7, j = idx & 127;
        Mre[i * 129 + j] = ar[idx] + ar[j * 128 + i];
        Mim[i * 129 + j] = ai[idx] - ai[j * 128 + i] + (i == j ? 1.0f : 0.0f);
    }
    __syncthreads();

    const int i = t >> 3;   // row for elimination (8 threads per row)
    const int l8 = t & 7;

    for (int p = 0; p < 128; ++p) {
        // phase 1: everyone reads pivot + their f; threads<128 scale row p (j!=p)
        float pr = Mre[p * 129 + p], pi = Mim[p * 129 + p];
        float den = 1.0f / (pr * pr + pi * pi);
        float ir = pr * den, ii = -pi * den;
        float fr = 0.f, fi = 0.f;
        if (i != p) { fr = Mre[i * 129 + p]; fi = Mim[i * 129 + p]; }
        if (t < 128 && t != p) {
            float mr = Mre[p * 129 + t], mi = Mim[p * 129 + t];
            Mre[p * 129 + t] = mr * ir - mi * ii;
            Mim[p * 129 + t] = mr * ii + mi * ir;
        }
        __syncthreads();
        // phase 2: update rows i!=p; row p thread writes [p][p]=inv
        if (i == p) {
            if (l8 == 0) { Mre[p * 129 + p] = ir; Mim[p * 129 + p] = ii; }
        } else {
            #pragma unroll
            for (int c = 0; c < 16; ++c) {
                int j = l8 + 8 * c;
                if (j == p) {
                    Mre[i * 129 + j] = -(fr * ir - fi * ii);
                    Mim[i * 129 + j] = -(fr * ii + fi * ir);
                } else {
                    float mr = Mre[p * 129 + j], mi = Mim[p * 129 + j];
                    Mre[i * 129 + j] -= fr * mr - fi * mi;
                    Mim[i * 129 + j] -= fr * mi + fi * mr;
                }
            }
        }
        __syncthreads();
    }

    float* qre_t = qmat + L * 32768;
    float* qim_t = qre_t + 16384;
    for (int q = 0; q < 16; ++q) {
        int idx = t + 1024 * q;
        int k = idx >> 7, j = idx & 127;
        qre_t[idx] = (j == k ? 1.0f : 0.0f) + 2.0f * Mim[j * 129 + k];
        qim_t[idx] = -2.0f * Mre[j * 129 + k];
    }
}

// ---------------------------------------------------------------------------
// Fused edge MLP via bf16 MFMA.
// Tile = 64 edges. 512 threads = 8 waves: wave w -> edge group (w&3)*16,
// col half (w>>2)*64. W1^T/W2^T staged in LDS bf16, XOR-swizzled
// (col_bytes ^= (row&7)<<4) so stride-512B/256B fragment reads hit the
// b128 bank floor. C1 staged bf16 (acc layout != A layout), C2 staged f32
// in reused x-LDS for coalesced output + atomics.
// ---------------------------------------------------------------------------
__global__ __launch_bounds__(512) void edge_kernel(const float* __restrict__ h,
                                                   const int* __restrict__ ei,
                                                   const float* __restrict__ W_e1,
                                                   const float* __restrict__ b_e1,
                                                   const float* __restrict__ W_e2,
                                                   const float* __restrict__ b_e2,
                                                   float* __restrict__ ef_out,
                                                   float* __restrict__ agg) {
    __shared__ short xs[64 * 256];     // 32 KiB  x tile bf16 (also reused as C2 f32)
    __shared__ short c1s[64 * 128];    // 16 KiB  C1 bf16
    __shared__ short w1t[128 * 256];   // 64 KiB  W1^T bf16  [j][k]
    __shared__ short w2t[128 * 128];   // 32 KiB  W2^T bf16  [j][k]
    float* fxs = (float*)xs;

    const int t = threadIdx.x;
    const int lane = t & 63;
    const int w = t >> 6;
    const int eg = w & 3;              // edge group: edges eg*16 .. eg*16+15
    const int n0 = (w >> 2) * 64;      // column half
    const int l15 = lane & 15;
    const int kg = lane >> 4;          // 0..3

    // ---- stage W1^T, W2^T (transpose + bf16 + swizzle), once ----
    {
        const float4* w1_4 = (const float4*)W_e1;
        for (int q = 0; q < 16; ++q) {
            int idx4 = t + 512 * q;
            int k = idx4 >> 5, j4 = idx4 & 31;
            float4 v = w1_4[idx4];
            int j = j4 * 4;
            w1t[(j + 0) * 256 + (k ^ (((j + 0) & 7) << 3))] = (short)f2bf(v.x);
            w1t[(j + 1) * 256 + (k ^ (((j + 1) & 7) << 3))] = (short)f2bf(v.y);
            w1t[(j + 2) * 256 + (k ^ (((j + 2) & 7) << 3))] = (short)f2bf(v.z);
            w1t[(j + 3) * 256 + (k ^ (((j + 3) & 7) << 3))] = (short)f2bf(v.w);
        }
        const float4* w2_4 = (const float4*)W_e2;
        for (int q = 0; q < 8; ++q) {
            int idx4 = t + 512 * q;
            int k = idx4 >> 5, j4 = idx4 & 31;
            float4 v = w2_4[idx4];
            int j = j4 * 4;
            w2t[(j + 0) * 128 + (k ^ (((j + 0) & 7) << 3))] = (short)f2bf(v.x);
            w2t[(j + 1) * 128 + (k ^ (((j + 1) & 7) << 3))] = (short)f2bf(v.y);
            w2t[(j + 2) * 128 + (k ^ (((j + 2) & 7) << 3))] = (short)f2bf(v.z);
            w2t[(j + 3) * 128 + (k ^ (((j + 3) & 7) << 3))] = (short)f2bf(v.w);
        }
    }
    float bj1[4], bj2[4];
    #pragma unroll
    for (int nf = 0; nf < 4; ++nf) {
        bj1[nf] = b_e1[n0 + nf * 16 + l15];
        bj2[nf] = b_e2[n0 + nf * 16 + l15];
    }
    __syncthreads();

    const int e_l = t >> 3, f8 = t & 7;
    const float4* h4 = (const float4*)h;
    const int arow = eg * 16 + l15;
    const int aswz = (arow & 7) << 3;

    for (int tile = blockIdx.x; tile < N_EDGES / 64; tile += gridDim.x) {
        const int e0 = tile * 64;
        // ---- stage x = [h[row], h[col]] as bf16, swizzled ----
        {
            int ri = ei[e0 + e_l];
            int ci = ei[N_EDGES + e0 + e_l];
            #pragma unroll
            for (int q = 0; q < 8; ++q) {
                int u = f8 + 8 * q;
                float4 v = (u < 32) ? h4[(size_t)ri * 32 + u]
                                    : h4[(size_t)ci * 32 + (u - 32)];
                bf16x4v b;
                b.x = (short)f2bf(v.x); b.y = (short)f2bf(v.y);
                b.z = (short)f2bf(v.z); b.w = (short)f2bf(v.w);
                int idx = e_l * 256 + ((u * 4) ^ ((e_l & 7) << 3));
                *(bf16x4v*)&xs[idx] = b;
            }
        }
        __syncthreads();

        // ---- GEMM1: [64x256] @ [256x128] ----
        f32x4 acc[4];
        #pragma unroll
        for (int nf = 0; nf < 4; ++nf) acc[nf] = (f32x4){0.f, 0.f, 0.f, 0.f};
        #pragma unroll
        for (int s = 0; s < 8; ++s) {
            int k0 = s * 32 + kg * 8;
            bf16x8 a = *(const bf16x8*)&xs[arow * 256 + (k0 ^ aswz)];
            #pragma unroll
            for (int nf = 0; nf < 4; ++nf) {
                int brow = n0 + nf * 16 + l15;
                bf16x8 b = *(const bf16x8*)&w1t[brow * 256 + (k0 ^ ((brow & 7) << 3))];
                acc[nf] = __builtin_amdgcn_mfma_f32_16x16x32_bf16(a, b, acc[nf], 0, 0, 0);
            }
        }
        // bias + silu -> C1 bf16 (acc layout: row=(kg*4+r), col=l15)
        #pragma unroll
        for (int nf = 0; nf < 4; ++nf) {
            #pragma unroll
            for (int r = 0; r < 4; ++r) {
                int row = eg * 16 + kg * 4 + r;
                int j = n0 + nf * 16 + l15;
                c1s[row * 128 + (j ^ ((row & 7) << 3))] = (short)f2bf(silu_f(acc[nf][r] + bj1[nf]));
            }
        }
        __syncthreads();

        // ---- GEMM2: [64x128] @ [128x128] ----
        f32x4 acc2[4];
        #pragma unroll
        for (int nf = 0; nf < 4; ++nf) acc2[nf] = (f32x4){0.f, 0.f, 0.f, 0.f};
        #pragma unroll
        for (int s = 0; s < 4; ++s) {
            int k0 = s * 32 + kg * 8;
            bf16x8 a = *(const bf16x8*)&c1s[arow * 128 + (k0 ^ aswz)];
            #pragma unroll
            for (int nf = 0; nf < 4; ++nf) {
                int brow = n0 + nf * 16 + l15;
                bf16x8 b = *(const bf16x8*)&w2t[brow * 128 + (k0 ^ ((brow & 7) << 3))];
                acc2[nf] = __builtin_amdgcn_mfma_f32_16x16x32_bf16(a, b, acc2[nf], 0, 0, 0);
            }
        }
        // bias + silu -> C2 f32 into reused x LDS (swizzle (row&31)<<2 floats)
        #pragma unroll
        for (int nf = 0; nf < 4; ++nf) {
            #pragma unroll
            for (int r = 0; r < 4; ++r) {
                int row = eg * 16 + kg * 4 + r;
                int j = n0 + nf * 16 + l15;
                fxs[row * 128 + (j ^ ((row & 31) << 2))] = silu_f(acc2[nf][r] + bj2[nf]);
            }
        }
        __syncthreads();

        // ---- output: coalesced ef_out store + fp32 atomics into agg ----
        {
            int e = t >> 3;
            int rw = ei[e0 + e];
            int sw = (e & 31) << 2;
            #pragma unroll
            for (int q = 0; q < 4; ++q) {
                int c4 = (t & 7) + 8 * q;
                float4 v = *(float4*)&fxs[e * 128 + ((c4 * 4) ^ sw)];
                *(float4*)(ef_out + (size_t)(e0 + e) * 128 + c4 * 4) = v;
                float* ap = agg + (size_t)rw * 128 + c4 * 4;
                atomicAdd(ap + 0, v.x);
                atomicAdd(ap + 1, v.y);
                atomicAdd(ap + 2, v.z);
                atomicAdd(ap + 3, v.w);
            }
        }
        __syncthreads();
    }
}

// ---------------------------------------------------------------------------
// Encode: q = [h, agg] @ W_enc + b_enc ; psi_re = q / ||q||
// ---------------------------------------------------------------------------
__global__ __launch_bounds__(256) void encode_kernel(const float* __restrict__ h,
                                                     const float* __restrict__ agg,
                                                     const float* __restrict__ W_enc,
                                                     const float* __restrict__ b_enc,
                                                     float* __restrict__ psi_re) {
    __shared__ float wl[256 * 128];   // 128 KiB
    __shared__ float xb[16 * 256];    // 16 KiB
    __shared__ float qb[16 * 128];    // 8 KiB
    __shared__ float nrm[16];
    const int t = threadIdx.x;
    const int j = t & 127;
    const int g = t >> 7;
    {
        float4* wl4 = (float4*)wl;
        const float4* we4 = (const float4*)W_enc;
        for (int q = 0; q < 32; ++q) wl4[t + 256 * q] = we4[t + 256 * q];
    }
    const float bj = b_enc[j];
    const float4* h4 = (const float4*)h;
    const float4* a4 = (const float4*)agg;
    float4* xb4 = (float4*)xb;
    __syncthreads();

    for (int tile = blockIdx.x; tile < N_NODES / 16; tile += gridDim.x) {
        const int n0 = tile * 16;
        #pragma unroll
        for (int p = 0; p < 4; ++p) {
            int idx = t + 256 * p;
            int r = idx >> 6, u = idx & 63;
            xb4[idx] = (u < 32) ? h4[(size_t)(n0 + r) * 32 + u]
                                : a4[(size_t)(n0 + r) * 32 + (u - 32)];
        }
        __syncthreads();
        float acc[8] = {0, 0, 0, 0, 0, 0, 0, 0};
        for (int k4 = 0; k4 < 64; ++k4) {
            float w0 = wl[(k4 * 4 + 0) * 128 + j];
            float w1 = wl[(k4 * 4 + 1) * 128 + j];
            float w2 = wl[(k4 * 4 + 2) * 128 + j];
            float w3 = wl[(k4 * 4 + 3) * 128 + j];
            #pragma unroll
            for (int rr = 0; rr < 8; ++rr) {
                float4 x = xb4[(g * 8 + rr) * 64 + k4];
                acc[rr] += x.x * w0 + x.y * w1 + x.z * w2 + x.w * w3;
            }
        }
        #pragma unroll
        for (int rr = 0; rr < 8; ++rr) {
            acc[rr] += bj;
            qb[(g * 8 + rr) * 128 + j] = acc[rr];
        }
        __syncthreads();
        {
            int r2 = t >> 4, l = t & 15;
            float s = 0.f;
            #pragma unroll
            for (int m = 0; m < 8; ++m) { float v = qb[r2 * 128 + l + 16 * m]; s += v * v; }
            s += __shfl_xor(s, 1);
            s += __shfl_xor(s, 2);
            s += __shfl_xor(s, 4);
            s += __shfl_xor(s, 8);
            if (l == 0) nrm[r2] = 1.0f / sqrtf(s + 1e-12f);
        }
        __syncthreads();
        #pragma unroll
        for (int rr = 0; rr < 8; ++rr) {
            psi_re[(size_t)(n0 + g * 8 + rr) * 128 + j] = acc[rr] * nrm[g * 8 + rr];
        }
        __syncthreads();
    }
}

// ---------------------------------------------------------------------------
// Evolve one layer: psi = CNOT( G^{x7}( psi @ Q^T ) )
// ---------------------------------------------------------------------------
template <int LAYER>
__global__ __launch_bounds__(256) void evolve_kernel(float* __restrict__ psi_re,
                                                     float* __restrict__ psi_im,
                                                     const float* __restrict__ qre_t,
                                                     const float* __restrict__ qim_t,
                                                     const float* __restrict__ coeffs) {
    __shared__ float qre_l[16384];   // 64 KiB, [k][j] = Q[j][k]
    __shared__ float qim_l[16384];   // 64 KiB
    __shared__ float2 bufA[8 * 128]; // 8 KiB
    __shared__ float2 bufB[8 * 128]; // 8 KiB
    const int t = threadIdx.x;
    const int j = t & 127;
    const int g = t >> 7;
    {
        float4* d = (float4*)qre_l;
        const float4* s_ = (const float4*)qre_t;
        for (int q = 0; q < 16; ++q) d[t + 256 * q] = s_[t + 256 * q];
        d = (float4*)qim_l;
        s_ = (const float4*)qim_t;
        for (int q = 0; q < 16; ++q) d[t + 256 * q] = s_[t + 256 * q];
    }
    const float tx = coeffs[2 * LAYER + 0] * 0.5f;
    const float ty = coeffs[2 * LAYER + 1] * 0.5f;
    const float cx = cosf(tx), sx = sinf(tx), cy = cosf(ty), sy = sinf(ty);
    const float G00r = cx * cy, G00i = sx * sy;
    const float G01r = -cx * sy, G01i = -sx * cy;
    const float G10r = cx * sy, G10i = -sx * cy;
    const float G11r = cx * cy, G11i = -sx * sy;
    int src = j;
    {
        const int cs[7] = {6, 5, 4, 3, 2, 1, 0};
        const int ts[7] = {0, 6, 5, 4, 3, 2, 1};
        #pragma unroll
        for (int m = 0; m < 7; ++m) {
            int cbit = 1 << (6 - cs[m]);
            int tbit = 1 << (6 - ts[m]);
            if (src & cbit) src ^= tbit;
        }
    }
    __syncthreads();

    for (int tile = blockIdx.x; tile < N_NODES / 8; tile += gridDim.x) {
        const int n0 = tile * 8;
        #pragma unroll
        for (int p = 0; p < 4; ++p) {
            int r = p * 2 + g;
            float re = psi_re[(size_t)(n0 + r) * 128 + j];
            float im = LAYER ? psi_im[(size_t)(n0 + r) * 128 + j] : 0.0f;
            bufA[r * 128 + j] = make_float2(re, im);
        }
        __syncthreads();
        float arr[4] = {0, 0, 0, 0}, aii[4] = {0, 0, 0, 0};
        for (int k = 0; k < 128; ++k) {
            float qr = qre_l[k * 128 + j];
            float qi = qim_l[k * 128 + j];
            #pragma unroll
            for (int r = 0; r < 4; ++r) {
                float2 x = bufA[(g * 4 + r) * 128 + k];
                arr[r] += x.x * qr;
                aii[r] += x.x * qi;
                if (LAYER) { arr[r] -= x.y * qi; aii[r] += x.y * qr; }
            }
        }
        #pragma unroll
        for (int r = 0; r < 4; ++r) bufB[(g * 4 + r) * 128 + j] = make_float2(arr[r], aii[r]);
        __syncthreads();
        float2* sb = bufB;
        float2* db = bufA;
        #pragma unroll
        for (int stage = 0; stage < 7; ++stage) {
            const int b = 1 << stage;
            const bool hi = (j & b) != 0;
            const float cor = hi ? G11r : G00r, coi = hi ? G11i : G00i;
            const float cpr = hi ? G10r : G01r, cpi = hi ? G10i : G01i;
            #pragma unroll
            for (int r = 0; r < 4; ++r) {
                int row = g * 4 + r;
                float2 v1 = sb[row * 128 + j];
                float2 v2 = sb[row * 128 + (j ^ b)];
                float nr = cor * v1.x - coi * v1.y + cpr * v2.x - cpi * v2.y;
                float ni = cor * v1.y + coi * v1.x + cpr * v2.y + cpi * v2.x;
                db[row * 128 + j] = make_float2(nr, ni);
            }
            __syncthreads();
            float2* tmp = sb; sb = db; db = tmp;
        }
        #pragma unroll
        for (int r = 0; r < 4; ++r) {
            int row = g * 4 + r;
            float2 v = sb[row * 128 + src];
            psi_re[(size_t)(n0 + row) * 128 + j] = v.x;
            psi_im[(size_t)(n0 + row) * 128 + j] = v.y;
        }
        __syncthreads();
    }
}

// ---------------------------------------------------------------------------
// Decode: out = h + psi_re @ W_dec + b_dec
// ---------------------------------------------------------------------------
__global__ __launch_bounds__(256) void decode_kernel(const float* __restrict__ psi_re,
                                                     const float* __restrict__ h,
                                                     const float* __restrict__ W_dec,
                                                     const float* __restrict__ b_dec,
                                                     float* __restrict__ out) {
    __shared__ float wl[128 * 128];  // 64 KiB
    __shared__ float xb[16 * 128];   // 8 KiB
    const int t = threadIdx.x;
    const int j = t & 127;
    const int g = t >> 7;
    {
        float4* wl4 = (float4*)wl;
        const float4* wd4 = (const float4*)W_dec;
        for (int q = 0; q < 16; ++q) wl4[t + 256 * q] = wd4[t + 256 * q];
    }
    const float bj = b_dec[j];
    const float4* p4 = (const float4*)psi_re;
    float4* xb4 = (float4*)xb;
    __syncthreads();

    for (int tile = blockIdx.x; tile < N_NODES / 16; tile += gridDim.x) {
        const int n0 = tile * 16;
        #pragma unroll
        for (int p = 0; p < 2; ++p) {
            int idx = t + 256 * p;
            int r = idx >> 5, u = idx & 31;
            xb4[idx] = p4[(size_t)(n0 + r) * 32 + u];
        }
        __syncthreads();
        float acc[8] = {0, 0, 0, 0, 0, 0, 0, 0};
        for (int k4 = 0; k4 < 32; ++k4) {
            float w0 = wl[(k4 * 4 + 0) * 128 + j];
            float w1 = wl[(k4 * 4 + 1) * 128 + j];
            float w2 = wl[(k4 * 4 + 2) * 128 + j];
            float w3 = wl[(k4 * 4 + 3) * 128 + j];
            #pragma unroll
            for (int rr = 0; rr < 8; ++rr) {
                float4 x = xb4[(g * 8 + rr) * 32 + k4];
                acc[rr] += x.x * w0 + x.y * w1 + x.z * w2 + x.w * w3;
            }
        }
        #pragma unroll
        for (int rr = 0; rr < 8; ++rr) {
            size_t n = (size_t)(n0 + g * 8 + rr);
            out[n * 128 + j] = h[n * 128 + j] + acc[rr] + bj;
        }
        __syncthreads();
    }
}

// ---------------------------------------------------------------------------
extern "C" void kernel_launch(void* const* d_in, const int* in_sizes, int n_in,
                              void* d_out, int out_size, void* d_ws, size_t ws_size,
                              hipStream_t stream) {
    const float* h      = (const float*)d_in[0];
    const int*   ei     = (const int*)d_in[1];
    const float* W_e1   = (const float*)d_in[2];
    const float* b_e1   = (const float*)d_in[3];
    const float* W_e2   = (const float*)d_in[4];
    const float* b_e2   = (const float*)d_in[5];
    const float* W_enc  = (const float*)d_in[6];
    const float* b_enc  = (const float*)d_in[7];
    const float* coeffs = (const float*)d_in[8];
    const float* A_real = (const float*)d_in[9];
    const float* A_imag = (const float*)d_in[10];
    const float* W_dec  = (const float*)d_in[11];
    const float* b_dec  = (const float*)d_in[12];

    float* out    = (float*)d_out;                 // N*128
    float* ef_out = out + (size_t)N_NODES * 128;   // E*128

    float* ws     = (float*)d_ws;
    float* agg    = ws;                              // 6.4M floats
    float* psi_re = ws + (size_t)N_NODES * 128;      // 6.4M
    float* psi_im = psi_re + (size_t)N_NODES * 128;  // 6.4M
    float* qmat   = psi_im + (size_t)N_NODES * 128;  // 2 * 32768 floats

    hipMemsetAsync(agg, 0, (size_t)N_NODES * 128 * sizeof(float), stream);

    cayley_kernel<<<2, 1024, 0, stream>>>(A_real, A_imag, qmat);

    edge_kernel<<<256, 512, 0, stream>>>(h, ei, W_e1, b_e1, W_e2, b_e2, ef_out, agg);

    encode_kernel<<<256, 256, 0, stream>>>(h, agg, W_enc, b_enc, psi_re);

    evolve_kernel<0><<<256, 256, 0, stream>>>(psi_re, psi_im, qmat, qmat + 16384, coeffs);
    evolve_kernel<1><<<256, 256, 0, stream>>>(psi_re, psi_im, qmat + 32768, qmat + 49152, coeffs);

    decode_kernel<<<512, 256, 0, stream>>>(psi_re, h, W_dec, b_dec, out);
}

// Round 3
// 1400.919 us; speedup vs baseline: 2.5226x; 1.9037x over previous
//
#include <hip/hip_runtime.h>
#include <math.h>

#define N_NODES 50000
#define N_EDGES 800000

typedef __attribute__((ext_vector_type(8))) short bf16x8;
typedef __attribute__((ext_vector_type(4))) float f32x4;

__device__ __forceinline__ float silu_f(float x) {
    return x / (1.0f + __expf(-x));
}

__device__ __forceinline__ unsigned short f2bf(float x) {
    union { float f; unsigned u; } v; v.f = x;
    unsigned r = v.u + 0x7FFFu + ((v.u >> 16) & 1u);
    return (unsigned short)(r >> 16);
}

// ---------------------------------------------------------------------------
// h (f32) -> h_bf (bf16), once. 8 elems/thread.
// ---------------------------------------------------------------------------
__global__ __launch_bounds__(256) void hbf16_kernel(const float* __restrict__ h,
                                                    short* __restrict__ hbf) {
    int i = blockIdx.x * 256 + threadIdx.x;   // 800000 threads, 8 elems each
    const float4* h4 = (const float4*)h;
    float4 v0 = h4[i * 2], v1 = h4[i * 2 + 1];
    bf16x8 b;
    b[0] = (short)f2bf(v0.x); b[1] = (short)f2bf(v0.y);
    b[2] = (short)f2bf(v0.z); b[3] = (short)f2bf(v0.w);
    b[4] = (short)f2bf(v1.x); b[5] = (short)f2bf(v1.y);
    b[6] = (short)f2bf(v1.z); b[7] = (short)f2bf(v1.w);
    ((bf16x8*)hbf)[i] = b;
}

// ---------------------------------------------------------------------------
// Cayley + fold gates & CNOT:  Q' = S * G^{\otimes 7} * (I - 2i*inv(M)),
// M = (A + A^H) + iI.  Gauss-Jordan in LDS (stride 129), then 7 butterfly
// stages on the ROW index, then CNOT row-gather. Output plain [i][k].
// ---------------------------------------------------------------------------
__global__ __launch_bounds__(1024) void cayley_kernel(const float* __restrict__ A_real,
                                                      const float* __restrict__ A_imag,
                                                      const float* __restrict__ coeffs,
                                                      float* __restrict__ qmat) {
    __shared__ float Mre[128 * 129];
    __shared__ float Mim[128 * 129];
    const int L = blockIdx.x;
    const int t = threadIdx.x;
    const float* ar = A_real + L * 16384;
    const float* ai = A_imag + L * 16384;

    for (int q = 0; q < 16; ++q) {
        int idx = t + 1024 * q;
        int i = idx >> 7, j = idx & 127;
        Mre[i * 129 + j] = ar[idx] + ar[j * 128 + i];
        Mim[i * 129 + j] = ai[idx] - ai[j * 128 + i] + (i == j ? 1.0f : 0.0f);
    }
    __syncthreads();

    const int i = t >> 3;
    const int l8 = t & 7;

    for (int p = 0; p < 128; ++p) {
        float pr = Mre[p * 129 + p], pi = Mim[p * 129 + p];
        float den = 1.0f / (pr * pr + pi * pi);
        float ir = pr * den, ii = -pi * den;
        float fr = 0.f, fi = 0.f;
        if (i != p) { fr = Mre[i * 129 + p]; fi = Mim[i * 129 + p]; }
        if (t < 128 && t != p) {
            float mr = Mre[p * 129 + t], mi = Mim[p * 129 + t];
            Mre[p * 129 + t] = mr * ir - mi * ii;
            Mim[p * 129 + t] = mr * ii + mi * ir;
        }
        __syncthreads();
        if (i == p) {
            if (l8 == 0) { Mre[p * 129 + p] = ir; Mim[p * 129 + p] = ii; }
        } else {
            #pragma unroll
            for (int c = 0; c < 16; ++c) {
                int j = l8 + 8 * c;
                if (j == p) {
                    Mre[i * 129 + j] = -(fr * ir - fi * ii);
                    Mim[i * 129 + j] = -(fr * ii + fi * ir);
                } else {
                    float mr = Mre[p * 129 + j], mi = Mim[p * 129 + j];
                    Mre[i * 129 + j] -= fr * mr - fi * mi;
                    Mim[i * 129 + j] -= fr * mi + fi * mr;
                }
            }
        }
        __syncthreads();
    }

    // inv(M) -> Q = I - 2i*inv(M)   (elementwise, in place)
    for (int q = 0; q < 16; ++q) {
        int idx = t + 1024 * q;
        int ii_ = idx >> 7, k = idx & 127;
        float invr = Mre[ii_ * 129 + k], invi = Mim[ii_ * 129 + k];
        Mre[ii_ * 129 + k] = (ii_ == k ? 1.0f : 0.0f) + 2.0f * invi;
        Mim[ii_ * 129 + k] = -2.0f * invr;
    }
    __syncthreads();

    // gate coefficients
    const float tx = coeffs[2 * L + 0] * 0.5f;
    const float ty = coeffs[2 * L + 1] * 0.5f;
    const float cx = cosf(tx), sx = sinf(tx), cy = cosf(ty), sy = sinf(ty);
    const float G00r = cx * cy, G00i = sx * sy;
    const float G01r = -cx * sy, G01i = -sx * cy;
    const float G10r = cx * sy, G10i = -sx * cy;
    const float G11r = cx * cy, G11i = -sx * sy;

    // 7 butterfly stages on row index (all columns in parallel)
    for (int st = 0; st < 7; ++st) {
        int b = 1 << st;
        #pragma unroll
        for (int p = 0; p < 8; ++p) {
            int pid = t + 1024 * p;
            int col = pid & 127, ph = pid >> 7;
            int i0 = ((ph >> st) << (st + 1)) | (ph & (b - 1));
            int i1 = i0 | b;
            float v0r = Mre[i0 * 129 + col], v0i = Mim[i0 * 129 + col];
            float v1r = Mre[i1 * 129 + col], v1i = Mim[i1 * 129 + col];
            Mre[i0 * 129 + col] = G00r * v0r - G00i * v0i + G01r * v1r - G01i * v1i;
            Mim[i0 * 129 + col] = G00r * v0i + G00i * v0r + G01r * v1i + G01i * v1r;
            Mre[i1 * 129 + col] = G10r * v0r - G10i * v0i + G11r * v1r - G11i * v1i;
            Mim[i1 * 129 + col] = G10r * v0i + G10i * v0r + G11r * v1i + G11i * v1r;
        }
        __syncthreads();
    }

    // CNOT row gather: new[i] = old[src(i)]
    const int cs[7] = {6, 5, 4, 3, 2, 1, 0};
    const int ts[7] = {0, 6, 5, 4, 3, 2, 1};
    float rr[16], rim[16];
    for (int q = 0; q < 16; ++q) {
        int idx = t + 1024 * q;
        int ii_ = idx >> 7, col = idx & 127;
        int s = ii_;
        #pragma unroll
        for (int m = 0; m < 7; ++m) {
            int cbit = 1 << (6 - cs[m]);
            int tbit = 1 << (6 - ts[m]);
            if (s & cbit) s ^= tbit;
        }
        rr[q] = Mre[s * 129 + col];
        rim[q] = Mim[s * 129 + col];
    }
    __syncthreads();
    float* qre = qmat + L * 32768;
    float* qim = qre + 16384;
    for (int q = 0; q < 16; ++q) {
        int idx = t + 1024 * q;
        int ii_ = idx >> 7, col = idx & 127;
        Mre[ii_ * 129 + col] = rr[q];
        Mim[ii_ * 129 + col] = rim[q];
        qre[idx] = rr[q];
        qim[idx] = rim[q];
    }
}

// ---------------------------------------------------------------------------
// ReM = Re(Q2' * Q1')  (complex product, real part only). 32 blocks x 512.
// ---------------------------------------------------------------------------
__global__ __launch_bounds__(512) void combine1_kernel(const float* __restrict__ qmat,
                                                       float* __restrict__ ReM) {
    __shared__ float q1r[16384];
    __shared__ float q1i[16384];
    const int t = threadIdx.x;
    const float* q1re = qmat;
    const float* q1im = qmat + 16384;
    const float* q2re = qmat + 32768;
    const float* q2im = qmat + 49152;
    for (int q = 0; q < 32; ++q) {
        q1r[t + 512 * q] = q1re[t + 512 * q];
        q1i[t + 512 * q] = q1im[t + 512 * q];
    }
    __syncthreads();
    int i = blockIdx.x * 4 + (t >> 7);
    int j = t & 127;
    float acc = 0.f;
    for (int k = 0; k < 128; ++k) {
        acc += q2re[i * 128 + k] * q1r[k * 128 + j] - q2im[i * 128 + k] * q1i[k * 128 + j];
    }
    ReM[i * 128 + j] = acc;
}

// ---------------------------------------------------------------------------
// D = Re(M)^T * W_dec.  32 blocks x 512.
// ---------------------------------------------------------------------------
__global__ __launch_bounds__(512) void combine2_kernel(const float* __restrict__ ReM,
                                                       const float* __restrict__ W_dec,
                                                       float* __restrict__ D) {
    __shared__ float ml[16384];
    __shared__ float wl[16384];
    const int t = threadIdx.x;
    for (int q = 0; q < 32; ++q) {
        ml[t + 512 * q] = ReM[t + 512 * q];
        wl[t + 512 * q] = W_dec[t + 512 * q];
    }
    __syncthreads();
    int k = blockIdx.x * 4 + (t >> 7);
    int j = t & 127;
    float acc = 0.f;
    for (int i = 0; i < 128; ++i) {
        acc += ml[i * 128 + k] * wl[i * 128 + j];
    }
    D[k * 128 + j] = acc;
}

// ---------------------------------------------------------------------------
// Barrier-free edge MLP. One wave = one 16-edge tile, all 128 output cols.
// Weights read-only in LDS (swizzled bf16); C1 transposed via per-wave LDS
// scratch (intra-wave lgkmcnt only). Outputs + atomics direct from acc.
// ---------------------------------------------------------------------------
__global__ __launch_bounds__(512) void edge_kernel(const short* __restrict__ hbf,
                                                   const int* __restrict__ ei,
                                                   const float* __restrict__ W_e1,
                                                   const float* __restrict__ b_e1,
                                                   const float* __restrict__ W_e2,
                                                   const float* __restrict__ b_e2,
                                                   float* __restrict__ ef_out,
                                                   float* __restrict__ agg) {
    __shared__ short w1t[128 * 256];   // 64 KiB  W1^T bf16 [j][k], swizzled
    __shared__ short w2t[128 * 128];   // 32 KiB  W2^T bf16 [j][k], swizzled
    __shared__ short c1s[8][2048];     // 32 KiB  per-wave 16x128 C1 scratch

    const int t = threadIdx.x;
    const int lane = t & 63;
    const int w = t >> 6;
    const int l15 = lane & 15;
    const int kg = lane >> 4;

    // ---- stage W1^T, W2^T (transpose + bf16 + swizzle), once ----
    {
        const float4* w1_4 = (const float4*)W_e1;
        for (int q = 0; q < 16; ++q) {
            int idx4 = t + 512 * q;
            int k = idx4 >> 5, j4 = idx4 & 31;
            float4 v = w1_4[idx4];
            int j = j4 * 4;
            w1t[(j + 0) * 256 + (k ^ (((j + 0) & 7) << 3))] = (short)f2bf(v.x);
            w1t[(j + 1) * 256 + (k ^ (((j + 1) & 7) << 3))] = (short)f2bf(v.y);
            w1t[(j + 2) * 256 + (k ^ (((j + 2) & 7) << 3))] = (short)f2bf(v.z);
            w1t[(j + 3) * 256 + (k ^ (((j + 3) & 7) << 3))] = (short)f2bf(v.w);
        }
        const float4* w2_4 = (const float4*)W_e2;
        for (int q = 0; q < 8; ++q) {
            int idx4 = t + 512 * q;
            int k = idx4 >> 5, j4 = idx4 & 31;
            float4 v = w2_4[idx4];
            int j = j4 * 4;
            w2t[(j + 0) * 128 + (k ^ (((j + 0) & 7) << 3))] = (short)f2bf(v.x);
            w2t[(j + 1) * 128 + (k ^ (((j + 1) & 7) << 3))] = (short)f2bf(v.y);
            w2t[(j + 2) * 128 + (k ^ (((j + 2) & 7) << 3))] = (short)f2bf(v.z);
            w2t[(j + 3) * 128 + (k ^ (((j + 3) & 7) << 3))] = (short)f2bf(v.w);
        }
    }
    float b1v[8], b2v[8];
    #pragma unroll
    for (int nf = 0; nf < 8; ++nf) {
        b1v[nf] = b_e1[nf * 16 + l15];
        b2v[nf] = b_e2[nf * 16 + l15];
    }
    __syncthreads();   // the ONLY block barrier

    const bf16x8* hb8 = (const bf16x8*)hbf;
    short* myc1 = &c1s[w][0];
    const int NW = gridDim.x * 8;
    const int wvid = blockIdx.x * 8 + w;
    const int nt = N_EDGES / 16;

    int tile = wvid;
    int ri = 0, ci = 0;
    if (tile < nt) {
        ri = ei[tile * 16 + l15];
        ci = ei[N_EDGES + tile * 16 + l15];
    }

    for (; tile < nt; ) {
        const int e0 = tile * 16;
        // ---- A1 fragments straight from global bf16 ----
        bf16x8 a1[8];
        #pragma unroll
        for (int s = 0; s < 4; ++s) a1[s] = hb8[(size_t)ri * 16 + s * 4 + kg];
        #pragma unroll
        for (int s = 0; s < 4; ++s) a1[4 + s] = hb8[(size_t)ci * 16 + s * 4 + kg];

        // prefetch next tile's indices
        const int tn = tile + NW;
        int ri2 = 0, ci2 = 0;
        if (tn < nt) {
            ri2 = ei[tn * 16 + l15];
            ci2 = ei[N_EDGES + tn * 16 + l15];
        }

        // ---- GEMM1: [16x256] @ [256x128] ----
        f32x4 acc[8];
        #pragma unroll
        for (int nf = 0; nf < 8; ++nf) acc[nf] = (f32x4){0.f, 0.f, 0.f, 0.f};
        #pragma unroll
        for (int s = 0; s < 8; ++s) {
            const int k0 = s * 32 + kg * 8;
            #pragma unroll
            for (int nf = 0; nf < 8; ++nf) {
                int brow = nf * 16 + l15;
                bf16x8 b = *(const bf16x8*)&w1t[brow * 256 + (k0 ^ ((brow & 7) << 3))];
                acc[nf] = __builtin_amdgcn_mfma_f32_16x16x32_bf16(a1[s], b, acc[nf], 0, 0, 0);
            }
        }

        // ---- bias+silu -> per-wave C1 scratch (bf16, swizzled) ----
        #pragma unroll
        for (int nf = 0; nf < 8; ++nf) {
            #pragma unroll
            for (int r = 0; r < 4; ++r) {
                int row = kg * 4 + r;
                int col = nf * 16 + l15;
                myc1[row * 128 + (col ^ ((row & 7) << 3))] =
                    (short)f2bf(silu_f(acc[nf][r] + b1v[nf]));
            }
        }

        // ---- A2 fragments from scratch (intra-wave dep, no barrier) ----
        bf16x8 a2[4];
        #pragma unroll
        for (int s2 = 0; s2 < 4; ++s2) {
            int k0 = s2 * 32 + kg * 8;
            a2[s2] = *(const bf16x8*)&myc1[l15 * 128 + (k0 ^ ((l15 & 7) << 3))];
        }

        // ---- GEMM2: [16x128] @ [128x128] ----
        f32x4 acc2[8];
        #pragma unroll
        for (int nf = 0; nf < 8; ++nf) acc2[nf] = (f32x4){0.f, 0.f, 0.f, 0.f};
        #pragma unroll
        for (int s2 = 0; s2 < 4; ++s2) {
            const int k0 = s2 * 32 + kg * 8;
            #pragma unroll
            for (int nf = 0; nf < 8; ++nf) {
                int brow = nf * 16 + l15;
                bf16x8 b = *(const bf16x8*)&w2t[brow * 128 + (k0 ^ ((brow & 7) << 3))];
                acc2[nf] = __builtin_amdgcn_mfma_f32_16x16x32_bf16(a2[s2], b, acc2[nf], 0, 0, 0);
            }
        }

        // ---- output: direct stores + atomics from acc layout ----
        int rw[4];
        #pragma unroll
        for (int r = 0; r < 4; ++r) rw[r] = __shfl(ri, kg * 4 + r);
        #pragma unroll
        for (int nf = 0; nf < 8; ++nf) {
            int col = nf * 16 + l15;
            #pragma unroll
            for (int r = 0; r < 4; ++r) {
                int erow = kg * 4 + r;
                float v = silu_f(acc2[nf][r] + b2v[nf]);
                ef_out[(size_t)(e0 + erow) * 128 + col] = v;
                atomicAdd(&agg[(size_t)rw[r] * 128 + col], v);
            }
        }

        tile = tn; ri = ri2; ci = ci2;
    }
}

// ---------------------------------------------------------------------------
// Encode: q = [h, agg] @ W_enc + b_enc ; v = q / ||q||
// ---------------------------------------------------------------------------
__global__ __launch_bounds__(256) void encode_kernel(const float* __restrict__ h,
                                                     const float* __restrict__ agg,
                                                     const float* __restrict__ W_enc,
                                                     const float* __restrict__ b_enc,
                                                     float* __restrict__ v_out) {
    __shared__ float wl[256 * 128];   // 128 KiB
    __shared__ float xb[16 * 256];    // 16 KiB
    __shared__ float qb[16 * 128];    // 8 KiB
    __shared__ float nrm[16];
    const int t = threadIdx.x;
    const int j = t & 127;
    const int g = t >> 7;
    {
        float4* wl4 = (float4*)wl;
        const float4* we4 = (const float4*)W_enc;
        for (int q = 0; q < 32; ++q) wl4[t + 256 * q] = we4[t + 256 * q];
    }
    const float bj = b_enc[j];
    const float4* h4 = (const float4*)h;
    const float4* a4 = (const float4*)agg;
    float4* xb4 = (float4*)xb;
    __syncthreads();

    for (int tile = blockIdx.x; tile < N_NODES / 16; tile += gridDim.x) {
        const int n0 = tile * 16;
        #pragma unroll
        for (int p = 0; p < 4; ++p) {
            int idx = t + 256 * p;
            int r = idx >> 6, u = idx & 63;
            xb4[idx] = (u < 32) ? h4[(size_t)(n0 + r) * 32 + u]
                                : a4[(size_t)(n0 + r) * 32 + (u - 32)];
        }
        __syncthreads();
        float acc[8] = {0, 0, 0, 0, 0, 0, 0, 0};
        for (int k4 = 0; k4 < 64; ++k4) {
            float w0 = wl[(k4 * 4 + 0) * 128 + j];
            float w1 = wl[(k4 * 4 + 1) * 128 + j];
            float w2 = wl[(k4 * 4 + 2) * 128 + j];
            float w3 = wl[(k4 * 4 + 3) * 128 + j];
            #pragma unroll
            for (int rr = 0; rr < 8; ++rr) {
                float4 x = xb4[(g * 8 + rr) * 64 + k4];
                acc[rr] += x.x * w0 + x.y * w1 + x.z * w2 + x.w * w3;
            }
        }
        #pragma unroll
        for (int rr = 0; rr < 8; ++rr) {
            acc[rr] += bj;
            qb[(g * 8 + rr) * 128 + j] = acc[rr];
        }
        __syncthreads();
        {
            int r2 = t >> 4, l = t & 15;
            float s = 0.f;
            #pragma unroll
            for (int m = 0; m < 8; ++m) { float vq = qb[r2 * 128 + l + 16 * m]; s += vq * vq; }
            s += __shfl_xor(s, 1);
            s += __shfl_xor(s, 2);
            s += __shfl_xor(s, 4);
            s += __shfl_xor(s, 8);
            if (l == 0) nrm[r2] = 1.0f / sqrtf(s + 1e-12f);
        }
        __syncthreads();
        #pragma unroll
        for (int rr = 0; rr < 8; ++rr) {
            v_out[(size_t)(n0 + g * 8 + rr) * 128 + j] = acc[rr] * nrm[g * 8 + rr];
        }
        __syncthreads();
    }
}

// ---------------------------------------------------------------------------
// Final: out = h + v @ D + b_dec   (evolve+decode collapsed into D)
// ---------------------------------------------------------------------------
__global__ __launch_bounds__(256) void decode_kernel(const float* __restrict__ v_in,
                                                     const float* __restrict__ h,
                                                     const float* __restrict__ D,
                                                     const float* __restrict__ b_dec,
                                                     float* __restrict__ out) {
    __shared__ float wl[128 * 128];  // 64 KiB
    __shared__ float xb[16 * 128];   // 8 KiB
    const int t = threadIdx.x;
    const int j = t & 127;
    const int g = t >> 7;
    {
        float4* wl4 = (float4*)wl;
        const float4* wd4 = (const float4*)D;
        for (int q = 0; q < 16; ++q) wl4[t + 256 * q] = wd4[t + 256 * q];
    }
    const float bj = b_dec[j];
    const float4* p4 = (const float4*)v_in;
    float4* xb4 = (float4*)xb;
    __syncthreads();

    for (int tile = blockIdx.x; tile < N_NODES / 16; tile += gridDim.x) {
        const int n0 = tile * 16;
        #pragma unroll
        for (int p = 0; p < 2; ++p) {
            int idx = t + 256 * p;
            int r = idx >> 5, u = idx & 31;
            xb4[idx] = p4[(size_t)(n0 + r) * 32 + u];
        }
        __syncthreads();
        float acc[8] = {0, 0, 0, 0, 0, 0, 0, 0};
        for (int k4 = 0; k4 < 32; ++k4) {
            float w0 = wl[(k4 * 4 + 0) * 128 + j];
            float w1 = wl[(k4 * 4 + 1) * 128 + j];
            float w2 = wl[(k4 * 4 + 2) * 128 + j];
            float w3 = wl[(k4 * 4 + 3) * 128 + j];
            #pragma unroll
            for (int rr = 0; rr < 8; ++rr) {
                float4 x = xb4[(g * 8 + rr) * 32 + k4];
                acc[rr] += x.x * w0 + x.y * w1 + x.z * w2 + x.w * w3;
            }
        }
        #pragma unroll
        for (int rr = 0; rr < 8; ++rr) {
            size_t n = (size_t)(n0 + g * 8 + rr);
            out[n * 128 + j] = h[n * 128 + j] + acc[rr] + bj;
        }
        __syncthreads();
    }
}

// ---------------------------------------------------------------------------
extern "C" void kernel_launch(void* const* d_in, const int* in_sizes, int n_in,
                              void* d_out, int out_size, void* d_ws, size_t ws_size,
                              hipStream_t stream) {
    const float* h      = (const float*)d_in[0];
    const int*   ei     = (const int*)d_in[1];
    const float* W_e1   = (const float*)d_in[2];
    const float* b_e1   = (const float*)d_in[3];
    const float* W_e2   = (const float*)d_in[4];
    const float* b_e2   = (const float*)d_in[5];
    const float* W_enc  = (const float*)d_in[6];
    const float* b_enc  = (const float*)d_in[7];
    const float* coeffs = (const float*)d_in[8];
    const float* A_real = (const float*)d_in[9];
    const float* A_imag = (const float*)d_in[10];
    const float* W_dec  = (const float*)d_in[11];
    const float* b_dec  = (const float*)d_in[12];

    float* out    = (float*)d_out;                 // N*128
    float* ef_out = out + (size_t)N_NODES * 128;   // E*128

    float* ws     = (float*)d_ws;
    float* agg    = ws;                                   // 6.4M floats
    float* v      = ws + (size_t)N_NODES * 128;           // 6.4M
    short* h_bf   = (short*)(v + (size_t)N_NODES * 128);  // 6.4M shorts (3.2M floats)
    float* qmat   = v + (size_t)N_NODES * 128 + (size_t)N_NODES * 64;
    float* ReM    = qmat + 65536;
    float* Dmat   = ReM + 16384;

    hipMemsetAsync(agg, 0, (size_t)N_NODES * 128 * sizeof(float), stream);

    hbf16_kernel<<<3125, 256, 0, stream>>>(h, h_bf);

    cayley_kernel<<<2, 1024, 0, stream>>>(A_real, A_imag, coeffs, qmat);
    combine1_kernel<<<32, 512, 0, stream>>>(qmat, ReM);
    combine2_kernel<<<32, 512, 0, stream>>>(ReM, W_dec, Dmat);

    edge_kernel<<<256, 512, 0, stream>>>(h_bf, ei, W_e1, b_e1, W_e2, b_e2, ef_out, agg);

    encode_kernel<<<256, 256, 0, stream>>>(h, agg, W_enc, b_enc, v);

    decode_kernel<<<512, 256, 0, stream>>>(v, h, Dmat, b_dec, out);
}

// Round 4
// 933.883 us; speedup vs baseline: 3.7842x; 1.5001x over previous
//
#include <hip/hip_runtime.h>
#include <math.h>

#define N_NODES 50000
#define N_EDGES 800000
#define NS_ITERS 4

typedef __attribute__((ext_vector_type(8))) short bf16x8;
typedef __attribute__((ext_vector_type(4))) float f32x4;

__device__ __forceinline__ float silu_f(float x) {
    return x / (1.0f + __expf(-x));
}

__device__ __forceinline__ unsigned short f2bf(float x) {
    union { float f; unsigned u; } v; v.f = x;
    unsigned r = v.u + 0x7FFFu + ((v.u >> 16) & 1u);
    return (unsigned short)(r >> 16);
}

// ---------------------------------------------------------------------------
// h (f32) -> h_bf (bf16), once. 8 elems/thread.
// ---------------------------------------------------------------------------
__global__ __launch_bounds__(256) void hbf16_kernel(const float* __restrict__ h,
                                                    short* __restrict__ hbf) {
    int i = blockIdx.x * 256 + threadIdx.x;
    const float4* h4 = (const float4*)h;
    float4 v0 = h4[i * 2], v1 = h4[i * 2 + 1];
    bf16x8 b;
    b[0] = (short)f2bf(v0.x); b[1] = (short)f2bf(v0.y);
    b[2] = (short)f2bf(v0.z); b[3] = (short)f2bf(v0.w);
    b[4] = (short)f2bf(v1.x); b[5] = (short)f2bf(v1.y);
    b[6] = (short)f2bf(v1.z); b[7] = (short)f2bf(v1.w);
    ((bf16x8*)hbf)[i] = b;
}

// ---------------------------------------------------------------------------
// H = A + A^H (no diagonal i term), and X0 = H - iI  (first-order inverse of
// M = H + iI).  2 blocks x 1024.
// Layout per layer L: re at buf + L*32768, im at buf + L*32768 + 16384.
// ---------------------------------------------------------------------------
__global__ __launch_bounds__(1024) void hmat_kernel(const float* __restrict__ A_real,
                                                    const float* __restrict__ A_imag,
                                                    float* __restrict__ H,
                                                    float* __restrict__ X) {
    const int L = blockIdx.x;
    const int t = threadIdx.x;
    const float* ar = A_real + L * 16384;
    const float* ai = A_imag + L * 16384;
    float* hre = H + L * 32768;
    float* him = hre + 16384;
    float* xre = X + L * 32768;
    float* xim = xre + 16384;
    for (int q = 0; q < 16; ++q) {
        int idx = t + 1024 * q;
        int i = idx >> 7, j = idx & 127;
        float hr = ar[idx] + ar[j * 128 + i];
        float hi = ai[idx] - ai[j * 128 + i];
        hre[idx] = hr;
        him[idx] = hi;
        xre[idx] = hr;
        xim[idx] = hi - (i == j ? 1.0f : 0.0f);
    }
}

// ---------------------------------------------------------------------------
// T = M X = H X + iX.   64 blocks x 512 (32 blocks/layer, 4 rows each).
// ---------------------------------------------------------------------------
__global__ __launch_bounds__(512) void ns_t_kernel(const float* __restrict__ H,
                                                   const float* __restrict__ X,
                                                   float* __restrict__ T) {
    const int L = blockIdx.x >> 5;
    const int t = threadIdx.x;
    const int i = (blockIdx.x & 31) * 4 + (t >> 7);
    const int j = t & 127;
    const float* hre = H + L * 32768;
    const float* him = hre + 16384;
    const float* xre = X + L * 32768;
    const float* xim = xre + 16384;
    float accr = 0.f, acci = 0.f;
    #pragma unroll 4
    for (int k = 0; k < 128; ++k) {
        float hr = hre[i * 128 + k], hi = him[i * 128 + k];
        float xr = xre[k * 128 + j], xi = xim[k * 128 + j];
        accr += hr * xr - hi * xi;
        acci += hr * xi + hi * xr;
    }
    // + i * X[i][j]
    T[L * 32768 + i * 128 + j]        = accr - xim[i * 128 + j];
    T[L * 32768 + 16384 + i * 128 + j] = acci + xre[i * 128 + j];
}

// ---------------------------------------------------------------------------
// Xout = 2X - X T.   64 blocks x 512.
// ---------------------------------------------------------------------------
__global__ __launch_bounds__(512) void ns_x_kernel(const float* __restrict__ X,
                                                   const float* __restrict__ T,
                                                   float* __restrict__ Xout) {
    const int L = blockIdx.x >> 5;
    const int t = threadIdx.x;
    const int i = (blockIdx.x & 31) * 4 + (t >> 7);
    const int j = t & 127;
    const float* xre = X + L * 32768;
    const float* xim = xre + 16384;
    const float* tre = T + L * 32768;
    const float* tim = tre + 16384;
    float accr = 0.f, acci = 0.f;
    #pragma unroll 4
    for (int k = 0; k < 128; ++k) {
        float xr = xre[i * 128 + k], xi = xim[i * 128 + k];
        float tr = tre[k * 128 + j], ti = tim[k * 128 + j];
        accr += xr * tr - xi * ti;
        acci += xr * ti + xi * tr;
    }
    Xout[L * 32768 + i * 128 + j]         = 2.0f * xre[i * 128 + j] - accr;
    Xout[L * 32768 + 16384 + i * 128 + j] = 2.0f * xim[i * 128 + j] - acci;
}

// ---------------------------------------------------------------------------
// Q = I - 2i*X ; apply G^{x7} butterflies on row index; CNOT row gather.
// Output Y per layer (re/im). 2 blocks x 1024, LDS stride 129.
// ---------------------------------------------------------------------------
__global__ __launch_bounds__(1024) void gateperm_kernel(const float* __restrict__ X,
                                                        const float* __restrict__ coeffs,
                                                        float* __restrict__ Y) {
    __shared__ float Mre[128 * 129];
    __shared__ float Mim[128 * 129];
    const int L = blockIdx.x;
    const int t = threadIdx.x;
    const float* xre = X + L * 32768;
    const float* xim = xre + 16384;

    for (int q = 0; q < 16; ++q) {
        int idx = t + 1024 * q;
        int i = idx >> 7, j = idx & 127;
        Mre[i * 129 + j] = (i == j ? 1.0f : 0.0f) + 2.0f * xim[idx];
        Mim[i * 129 + j] = -2.0f * xre[idx];
    }
    __syncthreads();

    const float tx = coeffs[2 * L + 0] * 0.5f;
    const float ty = coeffs[2 * L + 1] * 0.5f;
    const float cx = cosf(tx), sx = sinf(tx), cy = cosf(ty), sy = sinf(ty);
    const float G00r = cx * cy, G00i = sx * sy;
    const float G01r = -cx * sy, G01i = -sx * cy;
    const float G10r = cx * sy, G10i = -sx * cy;
    const float G11r = cx * cy, G11i = -sx * sy;

    for (int st = 0; st < 7; ++st) {
        int b = 1 << st;
        #pragma unroll
        for (int p = 0; p < 8; ++p) {
            int pid = t + 1024 * p;
            int col = pid & 127, ph = pid >> 7;
            int i0 = ((ph >> st) << (st + 1)) | (ph & (b - 1));
            int i1 = i0 | b;
            float v0r = Mre[i0 * 129 + col], v0i = Mim[i0 * 129 + col];
            float v1r = Mre[i1 * 129 + col], v1i = Mim[i1 * 129 + col];
            Mre[i0 * 129 + col] = G00r * v0r - G00i * v0i + G01r * v1r - G01i * v1i;
            Mim[i0 * 129 + col] = G00r * v0i + G00i * v0r + G01r * v1i + G01i * v1r;
            Mre[i1 * 129 + col] = G10r * v0r - G10i * v0i + G11r * v1r - G11i * v1i;
            Mim[i1 * 129 + col] = G10r * v0i + G10i * v0r + G11r * v1i + G11i * v1r;
        }
        __syncthreads();
    }

    const int cs[7] = {6, 5, 4, 3, 2, 1, 0};
    const int ts[7] = {0, 6, 5, 4, 3, 2, 1};
    float* yre = Y + L * 32768;
    float* yim = yre + 16384;
    for (int q = 0; q < 16; ++q) {
        int idx = t + 1024 * q;
        int ii_ = idx >> 7, col = idx & 127;
        int s = ii_;
        #pragma unroll
        for (int m = 0; m < 7; ++m) {
            int cbit = 1 << (6 - cs[m]);
            int tbit = 1 << (6 - ts[m]);
            if (s & cbit) s ^= tbit;
        }
        yre[idx] = Mre[s * 129 + col];
        yim[idx] = Mim[s * 129 + col];
    }
}

// ---------------------------------------------------------------------------
// ReM = Re(Y2 * Y1). 32 blocks x 512.
// ---------------------------------------------------------------------------
__global__ __launch_bounds__(512) void combine1_kernel(const float* __restrict__ Y,
                                                       float* __restrict__ ReM) {
    __shared__ float q1r[16384];
    __shared__ float q1i[16384];
    const int t = threadIdx.x;
    const float* q1re = Y;
    const float* q1im = Y + 16384;
    const float* q2re = Y + 32768;
    const float* q2im = Y + 49152;
    for (int q = 0; q < 32; ++q) {
        q1r[t + 512 * q] = q1re[t + 512 * q];
        q1i[t + 512 * q] = q1im[t + 512 * q];
    }
    __syncthreads();
    int i = blockIdx.x * 4 + (t >> 7);
    int j = t & 127;
    float acc = 0.f;
    for (int k = 0; k < 128; ++k) {
        acc += q2re[i * 128 + k] * q1r[k * 128 + j] - q2im[i * 128 + k] * q1i[k * 128 + j];
    }
    ReM[i * 128 + j] = acc;
}

// ---------------------------------------------------------------------------
// D = Re(M)^T * W_dec. 32 blocks x 512.
// ---------------------------------------------------------------------------
__global__ __launch_bounds__(512) void combine2_kernel(const float* __restrict__ ReM,
                                                       const float* __restrict__ W_dec,
                                                       float* __restrict__ D) {
    __shared__ float ml[16384];
    __shared__ float wl[16384];
    const int t = threadIdx.x;
    for (int q = 0; q < 32; ++q) {
        ml[t + 512 * q] = ReM[t + 512 * q];
        wl[t + 512 * q] = W_dec[t + 512 * q];
    }
    __syncthreads();
    int k = blockIdx.x * 4 + (t >> 7);
    int j = t & 127;
    float acc = 0.f;
    for (int i = 0; i < 128; ++i) {
        acc += ml[i * 128 + k] * wl[i * 128 + j];
    }
    D[k * 128 + j] = acc;
}

// ---------------------------------------------------------------------------
// Barrier-free edge MLP (unchanged from round 3 — validated).
// ---------------------------------------------------------------------------
__global__ __launch_bounds__(512) void edge_kernel(const short* __restrict__ hbf,
                                                   const int* __restrict__ ei,
                                                   const float* __restrict__ W_e1,
                                                   const float* __restrict__ b_e1,
                                                   const float* __restrict__ W_e2,
                                                   const float* __restrict__ b_e2,
                                                   float* __restrict__ ef_out,
                                                   float* __restrict__ agg) {
    __shared__ short w1t[128 * 256];
    __shared__ short w2t[128 * 128];
    __shared__ short c1s[8][2048];

    const int t = threadIdx.x;
    const int lane = t & 63;
    const int w = t >> 6;
    const int l15 = lane & 15;
    const int kg = lane >> 4;

    {
        const float4* w1_4 = (const float4*)W_e1;
        for (int q = 0; q < 16; ++q) {
            int idx4 = t + 512 * q;
            int k = idx4 >> 5, j4 = idx4 & 31;
            float4 v = w1_4[idx4];
            int j = j4 * 4;
            w1t[(j + 0) * 256 + (k ^ (((j + 0) & 7) << 3))] = (short)f2bf(v.x);
            w1t[(j + 1) * 256 + (k ^ (((j + 1) & 7) << 3))] = (short)f2bf(v.y);
            w1t[(j + 2) * 256 + (k ^ (((j + 2) & 7) << 3))] = (short)f2bf(v.z);
            w1t[(j + 3) * 256 + (k ^ (((j + 3) & 7) << 3))] = (short)f2bf(v.w);
        }
        const float4* w2_4 = (const float4*)W_e2;
        for (int q = 0; q < 8; ++q) {
            int idx4 = t + 512 * q;
            int k = idx4 >> 5, j4 = idx4 & 31;
            float4 v = w2_4[idx4];
            int j = j4 * 4;
            w2t[(j + 0) * 128 + (k ^ (((j + 0) & 7) << 3))] = (short)f2bf(v.x);
            w2t[(j + 1) * 128 + (k ^ (((j + 1) & 7) << 3))] = (short)f2bf(v.y);
            w2t[(j + 2) * 128 + (k ^ (((j + 2) & 7) << 3))] = (short)f2bf(v.z);
            w2t[(j + 3) * 128 + (k ^ (((j + 3) & 7) << 3))] = (short)f2bf(v.w);
        }
    }
    float b1v[8], b2v[8];
    #pragma unroll
    for (int nf = 0; nf < 8; ++nf) {
        b1v[nf] = b_e1[nf * 16 + l15];
        b2v[nf] = b_e2[nf * 16 + l15];
    }
    __syncthreads();

    const bf16x8* hb8 = (const bf16x8*)hbf;
    short* myc1 = &c1s[w][0];
    const int NW = gridDim.x * 8;
    const int wvid = blockIdx.x * 8 + w;
    const int nt = N_EDGES / 16;

    int tile = wvid;
    int ri = 0, ci = 0;
    if (tile < nt) {
        ri = ei[tile * 16 + l15];
        ci = ei[N_EDGES + tile * 16 + l15];
    }

    for (; tile < nt; ) {
        const int e0 = tile * 16;
        bf16x8 a1[8];
        #pragma unroll
        for (int s = 0; s < 4; ++s) a1[s] = hb8[(size_t)ri * 16 + s * 4 + kg];
        #pragma unroll
        for (int s = 0; s < 4; ++s) a1[4 + s] = hb8[(size_t)ci * 16 + s * 4 + kg];

        const int tn = tile + NW;
        int ri2 = 0, ci2 = 0;
        if (tn < nt) {
            ri2 = ei[tn * 16 + l15];
            ci2 = ei[N_EDGES + tn * 16 + l15];
        }

        f32x4 acc[8];
        #pragma unroll
        for (int nf = 0; nf < 8; ++nf) acc[nf] = (f32x4){0.f, 0.f, 0.f, 0.f};
        #pragma unroll
        for (int s = 0; s < 8; ++s) {
            const int k0 = s * 32 + kg * 8;
            #pragma unroll
            for (int nf = 0; nf < 8; ++nf) {
                int brow = nf * 16 + l15;
                bf16x8 b = *(const bf16x8*)&w1t[brow * 256 + (k0 ^ ((brow & 7) << 3))];
                acc[nf] = __builtin_amdgcn_mfma_f32_16x16x32_bf16(a1[s], b, acc[nf], 0, 0, 0);
            }
        }

        #pragma unroll
        for (int nf = 0; nf < 8; ++nf) {
            #pragma unroll
            for (int r = 0; r < 4; ++r) {
                int row = kg * 4 + r;
                int col = nf * 16 + l15;
                myc1[row * 128 + (col ^ ((row & 7) << 3))] =
                    (short)f2bf(silu_f(acc[nf][r] + b1v[nf]));
            }
        }

        bf16x8 a2[4];
        #pragma unroll
        for (int s2 = 0; s2 < 4; ++s2) {
            int k0 = s2 * 32 + kg * 8;
            a2[s2] = *(const bf16x8*)&myc1[l15 * 128 + (k0 ^ ((l15 & 7) << 3))];
        }

        f32x4 acc2[8];
        #pragma unroll
        for (int nf = 0; nf < 8; ++nf) acc2[nf] = (f32x4){0.f, 0.f, 0.f, 0.f};
        #pragma unroll
        for (int s2 = 0; s2 < 4; ++s2) {
            const int k0 = s2 * 32 + kg * 8;
            #pragma unroll
            for (int nf = 0; nf < 8; ++nf) {
                int brow = nf * 16 + l15;
                bf16x8 b = *(const bf16x8*)&w2t[brow * 128 + (k0 ^ ((brow & 7) << 3))];
                acc2[nf] = __builtin_amdgcn_mfma_f32_16x16x32_bf16(a2[s2], b, acc2[nf], 0, 0, 0);
            }
        }

        int rw[4];
        #pragma unroll
        for (int r = 0; r < 4; ++r) rw[r] = __shfl(ri, kg * 4 + r);
        #pragma unroll
        for (int nf = 0; nf < 8; ++nf) {
            int col = nf * 16 + l15;
            #pragma unroll
            for (int r = 0; r < 4; ++r) {
                int erow = kg * 4 + r;
                float v = silu_f(acc2[nf][r] + b2v[nf]);
                ef_out[(size_t)(e0 + erow) * 128 + col] = v;
                atomicAdd(&agg[(size_t)rw[r] * 128 + col], v);
            }
        }

        tile = tn; ri = ri2; ci = ci2;
    }
}

// ---------------------------------------------------------------------------
// Encode: q = [h, agg] @ W_enc + b_enc ; v = q / ||q||
// ---------------------------------------------------------------------------
__global__ __launch_bounds__(256) void encode_kernel(const float* __restrict__ h,
                                                     const float* __restrict__ agg,
                                                     const float* __restrict__ W_enc,
                                                     const float* __restrict__ b_enc,
                                                     float* __restrict__ v_out) {
    __shared__ float wl[256 * 128];
    __shared__ float xb[16 * 256];
    __shared__ float qb[16 * 128];
    __shared__ float nrm[16];
    const int t = threadIdx.x;
    const int j = t & 127;
    const int g = t >> 7;
    {
        float4* wl4 = (float4*)wl;
        const float4* we4 = (const float4*)W_enc;
        for (int q = 0; q < 32; ++q) wl4[t + 256 * q] = we4[t + 256 * q];
    }
    const float bj = b_enc[j];
    const float4* h4 = (const float4*)h;
    const float4* a4 = (const float4*)agg;
    float4* xb4 = (float4*)xb;
    __syncthreads();

    for (int tile = blockIdx.x; tile < N_NODES / 16; tile += gridDim.x) {
        const int n0 = tile * 16;
        #pragma unroll
        for (int p = 0; p < 4; ++p) {
            int idx = t + 256 * p;
            int r = idx >> 6, u = idx & 63;
            xb4[idx] = (u < 32) ? h4[(size_t)(n0 + r) * 32 + u]
                                : a4[(size_t)(n0 + r) * 32 + (u - 32)];
        }
        __syncthreads();
        float acc[8] = {0, 0, 0, 0, 0, 0, 0, 0};
        for (int k4 = 0; k4 < 64; ++k4) {
            float w0 = wl[(k4 * 4 + 0) * 128 + j];
            float w1 = wl[(k4 * 4 + 1) * 128 + j];
            float w2 = wl[(k4 * 4 + 2) * 128 + j];
            float w3 = wl[(k4 * 4 + 3) * 128 + j];
            #pragma unroll
            for (int rr = 0; rr < 8; ++rr) {
                float4 x = xb4[(g * 8 + rr) * 64 + k4];
                acc[rr] += x.x * w0 + x.y * w1 + x.z * w2 + x.w * w3;
            }
        }
        #pragma unroll
        for (int rr = 0; rr < 8; ++rr) {
            acc[rr] += bj;
            qb[(g * 8 + rr) * 128 + j] = acc[rr];
        }
        __syncthreads();
        {
            int r2 = t >> 4, l = t & 15;
            float s = 0.f;
            #pragma unroll
            for (int m = 0; m < 8; ++m) { float vq = qb[r2 * 128 + l + 16 * m]; s += vq * vq; }
            s += __shfl_xor(s, 1);
            s += __shfl_xor(s, 2);
            s += __shfl_xor(s, 4);
            s += __shfl_xor(s, 8);
            if (l == 0) nrm[r2] = 1.0f / sqrtf(s + 1e-12f);
        }
        __syncthreads();
        #pragma unroll
        for (int rr = 0; rr < 8; ++rr) {
            v_out[(size_t)(n0 + g * 8 + rr) * 128 + j] = acc[rr] * nrm[g * 8 + rr];
        }
        __syncthreads();
    }
}

// ---------------------------------------------------------------------------
// Final: out = h + v @ D + b_dec
// ---------------------------------------------------------------------------
__global__ __launch_bounds__(256) void decode_kernel(const float* __restrict__ v_in,
                                                     const float* __restrict__ h,
                                                     const float* __restrict__ D,
                                                     const float* __restrict__ b_dec,
                                                     float* __restrict__ out) {
    __shared__ float wl[128 * 128];
    __shared__ float xb[16 * 128];
    const int t = threadIdx.x;
    const int j = t & 127;
    const int g = t >> 7;
    {
        float4* wl4 = (float4*)wl;
        const float4* wd4 = (const float4*)D;
        for (int q = 0; q < 16; ++q) wl4[t + 256 * q] = wd4[t + 256 * q];
    }
    const float bj = b_dec[j];
    const float4* p4 = (const float4*)v_in;
    float4* xb4 = (float4*)xb;
    __syncthreads();

    for (int tile = blockIdx.x; tile < N_NODES / 16; tile += gridDim.x) {
        const int n0 = tile * 16;
        #pragma unroll
        for (int p = 0; p < 2; ++p) {
            int idx = t + 256 * p;
            int r = idx >> 5, u = idx & 31;
            xb4[idx] = p4[(size_t)(n0 + r) * 32 + u];
        }
        __syncthreads();
        float acc[8] = {0, 0, 0, 0, 0, 0, 0, 0};
        for (int k4 = 0; k4 < 32; ++k4) {
            float w0 = wl[(k4 * 4 + 0) * 128 + j];
            float w1 = wl[(k4 * 4 + 1) * 128 + j];
            float w2 = wl[(k4 * 4 + 2) * 128 + j];
            float w3 = wl[(k4 * 4 + 3) * 128 + j];
            #pragma unroll
            for (int rr = 0; rr < 8; ++rr) {
                float4 x = xb4[(g * 8 + rr) * 32 + k4];
                acc[rr] += x.x * w0 + x.y * w1 + x.z * w2 + x.w * w3;
            }
        }
        #pragma unroll
        for (int rr = 0; rr < 8; ++rr) {
            size_t n = (size_t)(n0 + g * 8 + rr);
            out[n * 128 + j] = h[n * 128 + j] + acc[rr] + bj;
        }
        __syncthreads();
    }
}

// ---------------------------------------------------------------------------
extern "C" void kernel_launch(void* const* d_in, const int* in_sizes, int n_in,
                              void* d_out, int out_size, void* d_ws, size_t ws_size,
                              hipStream_t stream) {
    const float* h      = (const float*)d_in[0];
    const int*   ei     = (const int*)d_in[1];
    const float* W_e1   = (const float*)d_in[2];
    const float* b_e1   = (const float*)d_in[3];
    const float* W_e2   = (const float*)d_in[4];
    const float* b_e2   = (const float*)d_in[5];
    const float* W_enc  = (const float*)d_in[6];
    const float* b_enc  = (const float*)d_in[7];
    const float* coeffs = (const float*)d_in[8];
    const float* A_real = (const float*)d_in[9];
    const float* A_imag = (const float*)d_in[10];
    const float* W_dec  = (const float*)d_in[11];
    const float* b_dec  = (const float*)d_in[12];

    float* out    = (float*)d_out;                 // N*128
    float* ef_out = out + (size_t)N_NODES * 128;   // E*128

    float* ws     = (float*)d_ws;
    float* agg    = ws;                                   // 6.4M floats
    float* v      = ws + (size_t)N_NODES * 128;           // 6.4M
    short* h_bf   = (short*)(v + (size_t)N_NODES * 128);  // 6.4M shorts
    float* small  = v + (size_t)N_NODES * 128 + (size_t)N_NODES * 64;
    float* Ybuf   = small;                 // 65536
    float* ReM    = Ybuf + 65536;          // 16384
    float* Dmat   = ReM + 16384;           // 16384
    float* Hbuf   = Dmat + 16384;          // 65536
    float* Xa     = Hbuf + 65536;          // 65536
    float* Xb     = Xa + 65536;            // 65536
    float* Tbuf   = Xb + 65536;            // 65536

    hipMemsetAsync(agg, 0, (size_t)N_NODES * 128 * sizeof(float), stream);

    hbf16_kernel<<<3125, 256, 0, stream>>>(h, h_bf);

    // --- D-matrix chain: Newton-Schulz inverse + gates + combines ---
    hmat_kernel<<<2, 1024, 0, stream>>>(A_real, A_imag, Hbuf, Xa);
    float* xc = Xa;
    float* xn = Xb;
    for (int it = 0; it < NS_ITERS; ++it) {
        ns_t_kernel<<<64, 512, 0, stream>>>(Hbuf, xc, Tbuf);
        ns_x_kernel<<<64, 512, 0, stream>>>(xc, Tbuf, xn);
        float* tmp = xc; xc = xn; xn = tmp;
    }
    gateperm_kernel<<<2, 1024, 0, stream>>>(xc, coeffs, Ybuf);
    combine1_kernel<<<32, 512, 0, stream>>>(Ybuf, ReM);
    combine2_kernel<<<32, 512, 0, stream>>>(ReM, W_dec, Dmat);

    edge_kernel<<<256, 512, 0, stream>>>(h_bf, ei, W_e1, b_e1, W_e2, b_e2, ef_out, agg);

    encode_kernel<<<256, 256, 0, stream>>>(h, agg, W_enc, b_enc, v);

    decode_kernel<<<512, 256, 0, stream>>>(v, h, Dmat, b_dec, out);
}

// Round 5
// 623.260 us; speedup vs baseline: 5.6702x; 1.4984x over previous
//
#include <hip/hip_runtime.h>
#include <math.h>

#define N_NODES 50000
#define N_EDGES 800000
#define NS_ITERS 3

typedef __attribute__((ext_vector_type(8))) short bf16x8;
typedef __attribute__((ext_vector_type(2))) short shortx2;
typedef __attribute__((ext_vector_type(4))) float f32x4;

__device__ __forceinline__ float silu_f(float x) {
    return x / (1.0f + __expf(-x));
}

__device__ __forceinline__ unsigned short f2bf(float x) {
    union { float f; unsigned u; } v; v.f = x;
    unsigned r = v.u + 0x7FFFu + ((v.u >> 16) & 1u);
    return (unsigned short)(r >> 16);
}

__device__ __forceinline__ void atomic_pk_add_bf16(short* addr, shortx2 v) {
    typedef shortx2 __attribute__((address_space(1)))* gp1;
    __builtin_amdgcn_global_atomic_fadd_v2bf16((gp1)(unsigned long long)addr, v);
}

// ---------------------------------------------------------------------------
// h (f32) -> h_bf (bf16), once. 8 elems/thread.
// ---------------------------------------------------------------------------
__global__ __launch_bounds__(256) void hbf16_kernel(const float* __restrict__ h,
                                                    short* __restrict__ hbf) {
    int i = blockIdx.x * 256 + threadIdx.x;
    const float4* h4 = (const float4*)h;
    float4 v0 = h4[i * 2], v1 = h4[i * 2 + 1];
    bf16x8 b;
    b[0] = (short)f2bf(v0.x); b[1] = (short)f2bf(v0.y);
    b[2] = (short)f2bf(v0.z); b[3] = (short)f2bf(v0.w);
    b[4] = (short)f2bf(v1.x); b[5] = (short)f2bf(v1.y);
    b[6] = (short)f2bf(v1.z); b[7] = (short)f2bf(v1.w);
    ((bf16x8*)hbf)[i] = b;
}

// ---------------------------------------------------------------------------
// H = A + A^H, X0 = H - iI  (first-order inverse of M = H + iI).
// ---------------------------------------------------------------------------
__global__ __launch_bounds__(1024) void hmat_kernel(const float* __restrict__ A_real,
                                                    const float* __restrict__ A_imag,
                                                    float* __restrict__ H,
                                                    float* __restrict__ X) {
    const int L = blockIdx.x;
    const int t = threadIdx.x;
    const float* ar = A_real + L * 16384;
    const float* ai = A_imag + L * 16384;
    float* hre = H + L * 32768;
    float* him = hre + 16384;
    float* xre = X + L * 32768;
    float* xim = xre + 16384;
    for (int q = 0; q < 16; ++q) {
        int idx = t + 1024 * q;
        int i = idx >> 7, j = idx & 127;
        float hr = ar[idx] + ar[j * 128 + i];
        float hi = ai[idx] - ai[j * 128 + i];
        hre[idx] = hr;
        him[idx] = hi;
        xre[idx] = hr;
        xim[idx] = hi - (i == j ? 1.0f : 0.0f);
    }
}

// ---------------------------------------------------------------------------
// T = M X = H X + iX.   64 blocks x 512.
// ---------------------------------------------------------------------------
__global__ __launch_bounds__(512) void ns_t_kernel(const float* __restrict__ H,
                                                   const float* __restrict__ X,
                                                   float* __restrict__ T) {
    const int L = blockIdx.x >> 5;
    const int t = threadIdx.x;
    const int i = (blockIdx.x & 31) * 4 + (t >> 7);
    const int j = t & 127;
    const float* hre = H + L * 32768;
    const float* him = hre + 16384;
    const float* xre = X + L * 32768;
    const float* xim = xre + 16384;
    float accr = 0.f, acci = 0.f;
    #pragma unroll 4
    for (int k = 0; k < 128; ++k) {
        float hr = hre[i * 128 + k], hi = him[i * 128 + k];
        float xr = xre[k * 128 + j], xi = xim[k * 128 + j];
        accr += hr * xr - hi * xi;
        acci += hr * xi + hi * xr;
    }
    T[L * 32768 + i * 128 + j]         = accr - xim[i * 128 + j];
    T[L * 32768 + 16384 + i * 128 + j] = acci + xre[i * 128 + j];
}

// ---------------------------------------------------------------------------
// Xout = 2X - X T.   64 blocks x 512.
// ---------------------------------------------------------------------------
__global__ __launch_bounds__(512) void ns_x_kernel(const float* __restrict__ X,
                                                   const float* __restrict__ T,
                                                   float* __restrict__ Xout) {
    const int L = blockIdx.x >> 5;
    const int t = threadIdx.x;
    const int i = (blockIdx.x & 31) * 4 + (t >> 7);
    const int j = t & 127;
    const float* xre = X + L * 32768;
    const float* xim = xre + 16384;
    const float* tre = T + L * 32768;
    const float* tim = tre + 16384;
    float accr = 0.f, acci = 0.f;
    #pragma unroll 4
    for (int k = 0; k < 128; ++k) {
        float xr = xre[i * 128 + k], xi = xim[i * 128 + k];
        float tr = tre[k * 128 + j], ti = tim[k * 128 + j];
        accr += xr * tr - xi * ti;
        acci += xr * ti + xi * tr;
    }
    Xout[L * 32768 + i * 128 + j]         = 2.0f * xre[i * 128 + j] - accr;
    Xout[L * 32768 + 16384 + i * 128 + j] = 2.0f * xim[i * 128 + j] - acci;
}

// ---------------------------------------------------------------------------
// Q = I - 2i*X ; G^{x7} butterflies on row index; CNOT row gather.
// ---------------------------------------------------------------------------
__global__ __launch_bounds__(1024) void gateperm_kernel(const float* __restrict__ X,
                                                        const float* __restrict__ coeffs,
                                                        float* __restrict__ Y) {
    __shared__ float Mre[128 * 129];
    __shared__ float Mim[128 * 129];
    const int L = blockIdx.x;
    const int t = threadIdx.x;
    const float* xre = X + L * 32768;
    const float* xim = xre + 16384;

    for (int q = 0; q < 16; ++q) {
        int idx = t + 1024 * q;
        int i = idx >> 7, j = idx & 127;
        Mre[i * 129 + j] = (i == j ? 1.0f : 0.0f) + 2.0f * xim[idx];
        Mim[i * 129 + j] = -2.0f * xre[idx];
    }
    __syncthreads();

    const float tx = coeffs[2 * L + 0] * 0.5f;
    const float ty = coeffs[2 * L + 1] * 0.5f;
    const float cx = cosf(tx), sx = sinf(tx), cy = cosf(ty), sy = sinf(ty);
    const float G00r = cx * cy, G00i = sx * sy;
    const float G01r = -cx * sy, G01i = -sx * cy;
    const float G10r = cx * sy, G10i = -sx * cy;
    const float G11r = cx * cy, G11i = -sx * sy;

    for (int st = 0; st < 7; ++st) {
        int b = 1 << st;
        #pragma unroll
        for (int p = 0; p < 8; ++p) {
            int pid = t + 1024 * p;
            int col = pid & 127, ph = pid >> 7;
            int i0 = ((ph >> st) << (st + 1)) | (ph & (b - 1));
            int i1 = i0 | b;
            float v0r = Mre[i0 * 129 + col], v0i = Mim[i0 * 129 + col];
            float v1r = Mre[i1 * 129 + col], v1i = Mim[i1 * 129 + col];
            Mre[i0 * 129 + col] = G00r * v0r - G00i * v0i + G01r * v1r - G01i * v1i;
            Mim[i0 * 129 + col] = G00r * v0i + G00i * v0r + G01r * v1i + G01i * v1r;
            Mre[i1 * 129 + col] = G10r * v0r - G10i * v0i + G11r * v1r - G11i * v1i;
            Mim[i1 * 129 + col] = G10r * v0i + G10i * v0r + G11r * v1i + G11i * v1r;
        }
        __syncthreads();
    }

    const int cs[7] = {6, 5, 4, 3, 2, 1, 0};
    const int ts[7] = {0, 6, 5, 4, 3, 2, 1};
    float* yre = Y + L * 32768;
    float* yim = yre + 16384;
    for (int q = 0; q < 16; ++q) {
        int idx = t + 1024 * q;
        int ii_ = idx >> 7, col = idx & 127;
        int s = ii_;
        #pragma unroll
        for (int m = 0; m < 7; ++m) {
            int cbit = 1 << (6 - cs[m]);
            int tbit = 1 << (6 - ts[m]);
            if (s & cbit) s ^= tbit;
        }
        yre[idx] = Mre[s * 129 + col];
        yim[idx] = Mim[s * 129 + col];
    }
}

// ---------------------------------------------------------------------------
// ReM = Re(Y2 * Y1). 32 blocks x 512.
// ---------------------------------------------------------------------------
__global__ __launch_bounds__(512) void combine1_kernel(const float* __restrict__ Y,
                                                       float* __restrict__ ReM) {
    __shared__ float q1r[16384];
    __shared__ float q1i[16384];
    const int t = threadIdx.x;
    const float* q1re = Y;
    const float* q1im = Y + 16384;
    const float* q2re = Y + 32768;
    const float* q2im = Y + 49152;
    for (int q = 0; q < 32; ++q) {
        q1r[t + 512 * q] = q1re[t + 512 * q];
        q1i[t + 512 * q] = q1im[t + 512 * q];
    }
    __syncthreads();
    int i = blockIdx.x * 4 + (t >> 7);
    int j = t & 127;
    float acc = 0.f;
    for (int k = 0; k < 128; ++k) {
        acc += q2re[i * 128 + k] * q1r[k * 128 + j] - q2im[i * 128 + k] * q1i[k * 128 + j];
    }
    ReM[i * 128 + j] = acc;
}

// ---------------------------------------------------------------------------
// Dt = (Re(M)^T * W_dec)^T in bf16: Dt[j][k] = sum_i ReM[i][k]*W_dec[i][j].
// ---------------------------------------------------------------------------
__global__ __launch_bounds__(512) void combine2_kernel(const float* __restrict__ ReM,
                                                       const float* __restrict__ W_dec,
                                                       short* __restrict__ Dt) {
    __shared__ float ml[16384];
    __shared__ float wl[16384];
    const int t = threadIdx.x;
    for (int q = 0; q < 32; ++q) {
        ml[t + 512 * q] = ReM[t + 512 * q];
        wl[t + 512 * q] = W_dec[t + 512 * q];
    }
    __syncthreads();
    int k = blockIdx.x * 4 + (t >> 7);
    int j = t & 127;
    float acc = 0.f;
    for (int i = 0; i < 128; ++i) {
        acc += ml[i * 128 + k] * wl[i * 128 + j];
    }
    Dt[j * 128 + k] = (short)f2bf(acc);
}

// ---------------------------------------------------------------------------
// Barrier-free edge MLP, 16 waves/block (1024 thr), 128 KiB LDS.
// Per-wave C1 scratch halved via two-phase GEMM2. bf16 pk atomics into agg.
// Nontemporal ef stores.
// ---------------------------------------------------------------------------
__global__ __launch_bounds__(1024, 4) void edge_kernel(const short* __restrict__ hbf,
                                                       const int* __restrict__ ei,
                                                       const float* __restrict__ W_e1,
                                                       const float* __restrict__ b_e1,
                                                       const float* __restrict__ W_e2,
                                                       const float* __restrict__ b_e2,
                                                       float* __restrict__ ef_out,
                                                       short* __restrict__ agg_bf) {
    __shared__ short w1t[128 * 256];   // 64 KiB
    __shared__ short w2t[128 * 128];   // 32 KiB
    __shared__ short c1s[16][1024];    // 32 KiB (2 KiB/wave, 16x64 half-tile)

    const int t = threadIdx.x;
    const int lane = t & 63;
    const int w = t >> 6;
    const int l15 = lane & 15;
    const int kg = lane >> 4;

    {
        const float4* w1_4 = (const float4*)W_e1;
        for (int q = 0; q < 8; ++q) {
            int idx4 = t + 1024 * q;
            int k = idx4 >> 5, j4 = idx4 & 31;
            float4 v = w1_4[idx4];
            int j = j4 * 4;
            w1t[(j + 0) * 256 + (k ^ (((j + 0) & 7) << 3))] = (short)f2bf(v.x);
            w1t[(j + 1) * 256 + (k ^ (((j + 1) & 7) << 3))] = (short)f2bf(v.y);
            w1t[(j + 2) * 256 + (k ^ (((j + 2) & 7) << 3))] = (short)f2bf(v.z);
            w1t[(j + 3) * 256 + (k ^ (((j + 3) & 7) << 3))] = (short)f2bf(v.w);
        }
        const float4* w2_4 = (const float4*)W_e2;
        for (int q = 0; q < 4; ++q) {
            int idx4 = t + 1024 * q;
            int k = idx4 >> 5, j4 = idx4 & 31;
            float4 v = w2_4[idx4];
            int j = j4 * 4;
            w2t[(j + 0) * 128 + (k ^ (((j + 0) & 7) << 3))] = (short)f2bf(v.x);
            w2t[(j + 1) * 128 + (k ^ (((j + 1) & 7) << 3))] = (short)f2bf(v.y);
            w2t[(j + 2) * 128 + (k ^ (((j + 2) & 7) << 3))] = (short)f2bf(v.z);
            w2t[(j + 3) * 128 + (k ^ (((j + 3) & 7) << 3))] = (short)f2bf(v.w);
        }
    }
    float b1v[8], b2v[8];
    #pragma unroll
    for (int nf = 0; nf < 8; ++nf) {
        b1v[nf] = b_e1[nf * 16 + l15];
        b2v[nf] = b_e2[nf * 16 + l15];
    }
    __syncthreads();   // only block barrier

    const bf16x8* hb8 = (const bf16x8*)hbf;
    short* myc1 = &c1s[w][0];
    const int NW = gridDim.x * 16;
    const int wvid = blockIdx.x * 16 + w;
    const int nt = N_EDGES / 16;

    int tile = wvid;
    int ri = 0, ci = 0;
    if (tile < nt) {
        ri = ei[tile * 16 + l15];
        ci = ei[N_EDGES + tile * 16 + l15];
    }

    for (; tile < nt; ) {
        const int e0 = tile * 16;
        bf16x8 a1[8];
        #pragma unroll
        for (int s = 0; s < 4; ++s) a1[s] = hb8[(size_t)ri * 16 + s * 4 + kg];
        #pragma unroll
        for (int s = 0; s < 4; ++s) a1[4 + s] = hb8[(size_t)ci * 16 + s * 4 + kg];

        const int tn = tile + NW;
        int ri2 = 0, ci2 = 0;
        if (tn < nt) {
            ri2 = ei[tn * 16 + l15];
            ci2 = ei[N_EDGES + tn * 16 + l15];
        }

        // ---- GEMM1: [16x256] @ [256x128] ----
        f32x4 acc[8];
        #pragma unroll
        for (int nf = 0; nf < 8; ++nf) acc[nf] = (f32x4){0.f, 0.f, 0.f, 0.f};
        #pragma unroll
        for (int s = 0; s < 8; ++s) {
            const int k0 = s * 32 + kg * 8;
            #pragma unroll
            for (int nf = 0; nf < 8; ++nf) {
                int brow = nf * 16 + l15;
                bf16x8 b = *(const bf16x8*)&w1t[brow * 256 + (k0 ^ ((brow & 7) << 3))];
                acc[nf] = __builtin_amdgcn_mfma_f32_16x16x32_bf16(a1[s], b, acc[nf], 0, 0, 0);
            }
        }

        // ---- GEMM2 in two 64-col phases through the 2 KiB scratch ----
        f32x4 acc2[8];
        #pragma unroll
        for (int nf = 0; nf < 8; ++nf) acc2[nf] = (f32x4){0.f, 0.f, 0.f, 0.f};
        #pragma unroll
        for (int half = 0; half < 2; ++half) {
            // write C1 cols half*64..half*64+63 (bias+silu, bf16, swizzled)
            #pragma unroll
            for (int nfh = 0; nfh < 4; ++nfh) {
                int nf = half * 4 + nfh;
                #pragma unroll
                for (int r = 0; r < 4; ++r) {
                    int row = kg * 4 + r;
                    int c = nfh * 16 + l15;   // col within half
                    myc1[row * 64 + (c ^ ((row & 7) << 3))] =
                        (short)f2bf(silu_f(acc[nf][r] + b1v[nf]));
                }
            }
            // consume: k-slices s2 = 2*half, 2*half+1
            #pragma unroll
            for (int s2l = 0; s2l < 2; ++s2l) {
                int k0h = s2l * 32 + kg * 8;            // within-half k
                bf16x8 a2 = *(const bf16x8*)&myc1[l15 * 64 + (k0h ^ ((l15 & 7) << 3))];
                int k0g = half * 64 + k0h;              // global k for B
                #pragma unroll
                for (int nf = 0; nf < 8; ++nf) {
                    int brow = nf * 16 + l15;
                    bf16x8 b = *(const bf16x8*)&w2t[brow * 128 + (k0g ^ ((brow & 7) << 3))];
                    acc2[nf] = __builtin_amdgcn_mfma_f32_16x16x32_bf16(a2, b, acc2[nf], 0, 0, 0);
                }
            }
        }

        // ---- output: nt stores + packed bf16 atomics ----
        int rw[4];
        #pragma unroll
        for (int r = 0; r < 4; ++r) rw[r] = __shfl(ri, kg * 4 + r);
        #pragma unroll
        for (int r = 0; r < 4; ++r) {
            int erow = kg * 4 + r;
            float* efp = ef_out + (size_t)(e0 + erow) * 128;
            short* agp = agg_bf + (size_t)rw[r] * 128;
            #pragma unroll
            for (int nf = 0; nf < 8; ++nf) {
                int col = nf * 16 + l15;
                float v = silu_f(acc2[nf][r] + b2v[nf]);
                __builtin_nontemporal_store(v, efp + col);
                float vn = __shfl_xor(v, 1);
                if ((l15 & 1) == 0) {
                    shortx2 pk;
                    pk.x = (short)f2bf(v);
                    pk.y = (short)f2bf(vn);
                    atomic_pk_add_bf16(agp + col, pk);
                }
            }
        }

        tile = tn; ri = ri2; ci = ci2;
    }
}

// ---------------------------------------------------------------------------
// Encode via MFMA: q = [h_bf, agg_bf] @ W_enc + b_enc ; v_bf = q/||q|| (bf16)
// Barrier-free after W staging; per-wave 16 nodes.
// ---------------------------------------------------------------------------
__global__ __launch_bounds__(512, 4) void encode_kernel(const short* __restrict__ hbf,
                                                        const short* __restrict__ agg_bf,
                                                        const float* __restrict__ W_enc,
                                                        const float* __restrict__ b_enc,
                                                        short* __restrict__ v_bf) {
    __shared__ short wet[128 * 256];   // 64 KiB  W_enc^T bf16 [j][k] swizzled

    const int t = threadIdx.x;
    const int lane = t & 63;
    const int w = t >> 6;
    const int l15 = lane & 15;
    const int kg = lane >> 4;

    {
        const float4* we4 = (const float4*)W_enc;
        for (int q = 0; q < 16; ++q) {
            int idx4 = t + 512 * q;
            int k = idx4 >> 5, j4 = idx4 & 31;
            float4 v = we4[idx4];
            int j = j4 * 4;
            wet[(j + 0) * 256 + (k ^ (((j + 0) & 7) << 3))] = (short)f2bf(v.x);
            wet[(j + 1) * 256 + (k ^ (((j + 1) & 7) << 3))] = (short)f2bf(v.y);
            wet[(j + 2) * 256 + (k ^ (((j + 2) & 7) << 3))] = (short)f2bf(v.z);
            wet[(j + 3) * 256 + (k ^ (((j + 3) & 7) << 3))] = (short)f2bf(v.w);
        }
    }
    float bj[8];
    #pragma unroll
    for (int nf = 0; nf < 8; ++nf) bj[nf] = b_enc[nf * 16 + l15];
    __syncthreads();

    const bf16x8* hb8 = (const bf16x8*)hbf;
    const bf16x8* ab8 = (const bf16x8*)agg_bf;
    const int NW = gridDim.x * 8;
    const int nt = N_NODES / 16;

    for (int tile = blockIdx.x * 8 + w; tile < nt; tile += NW) {
        const int node = tile * 16 + l15;
        bf16x8 a[8];
        #pragma unroll
        for (int s = 0; s < 4; ++s) a[s] = hb8[(size_t)node * 16 + s * 4 + kg];
        #pragma unroll
        for (int s = 0; s < 4; ++s) a[4 + s] = ab8[(size_t)node * 16 + s * 4 + kg];

        f32x4 acc[8];
        #pragma unroll
        for (int nf = 0; nf < 8; ++nf) acc[nf] = (f32x4){0.f, 0.f, 0.f, 0.f};
        #pragma unroll
        for (int s = 0; s < 8; ++s) {
            const int k0 = s * 32 + kg * 8;
            #pragma unroll
            for (int nf = 0; nf < 8; ++nf) {
                int brow = nf * 16 + l15;
                bf16x8 b = *(const bf16x8*)&wet[brow * 256 + (k0 ^ ((brow & 7) << 3))];
                acc[nf] = __builtin_amdgcn_mfma_f32_16x16x32_bf16(a[s], b, acc[nf], 0, 0, 0);
            }
        }

        // bias + row-norm (rows kg*4+r; reduce over the 16-lane l15 group)
        float nr[4] = {0.f, 0.f, 0.f, 0.f};
        #pragma unroll
        for (int nf = 0; nf < 8; ++nf) {
            #pragma unroll
            for (int r = 0; r < 4; ++r) {
                acc[nf][r] += bj[nf];
                nr[r] += acc[nf][r] * acc[nf][r];
            }
        }
        #pragma unroll
        for (int r = 0; r < 4; ++r) {
            nr[r] += __shfl_xor(nr[r], 1);
            nr[r] += __shfl_xor(nr[r], 2);
            nr[r] += __shfl_xor(nr[r], 4);
            nr[r] += __shfl_xor(nr[r], 8);
            nr[r] = 1.0f / sqrtf(nr[r] + 1e-12f);
        }
        #pragma unroll
        for (int r = 0; r < 4; ++r) {
            size_t rowb = (size_t)(tile * 16 + kg * 4 + r) * 128;
            #pragma unroll
            for (int nf = 0; nf < 8; ++nf) {
                v_bf[rowb + nf * 16 + l15] = (short)f2bf(acc[nf][r] * nr[r]);
            }
        }
    }
}

// ---------------------------------------------------------------------------
// Decode via MFMA: out = h + v_bf @ D + b_dec  (Dt staged bf16 in LDS)
// ---------------------------------------------------------------------------
__global__ __launch_bounds__(512, 4) void decode_kernel(const short* __restrict__ v_bf,
                                                        const float* __restrict__ h,
                                                        const short* __restrict__ Dt_bf,
                                                        const float* __restrict__ b_dec,
                                                        float* __restrict__ out) {
    __shared__ short dt[128 * 128];   // 32 KiB

    const int t = threadIdx.x;
    const int lane = t & 63;
    const int w = t >> 6;
    const int l15 = lane & 15;
    const int kg = lane >> 4;

    {
        const int4* s4 = (const int4*)Dt_bf;   // 2048 int4
        for (int q = 0; q < 4; ++q) {
            int idx4 = t + 512 * q;
            int j = idx4 >> 4, c = idx4 & 15;
            int k0 = c * 8;
            int4 v = s4[idx4];
            *(int4*)&dt[j * 128 + (k0 ^ ((j & 7) << 3))] = v;
        }
    }
    float bj[8];
    #pragma unroll
    for (int nf = 0; nf < 8; ++nf) bj[nf] = b_dec[nf * 16 + l15];
    __syncthreads();

    const bf16x8* vb8 = (const bf16x8*)v_bf;
    const int NW = gridDim.x * 8;
    const int nt = N_NODES / 16;

    for (int tile = blockIdx.x * 8 + w; tile < nt; tile += NW) {
        const int node = tile * 16 + l15;
        bf16x8 a[4];
        #pragma unroll
        for (int s = 0; s < 4; ++s) a[s] = vb8[(size_t)node * 16 + s * 4 + kg];

        f32x4 acc[8];
        #pragma unroll
        for (int nf = 0; nf < 8; ++nf) acc[nf] = (f32x4){0.f, 0.f, 0.f, 0.f};
        #pragma unroll
        for (int s = 0; s < 4; ++s) {
            const int k0 = s * 32 + kg * 8;
            #pragma unroll
            for (int nf = 0; nf < 8; ++nf) {
                int brow = nf * 16 + l15;
                bf16x8 b = *(const bf16x8*)&dt[brow * 128 + (k0 ^ ((brow & 7) << 3))];
                acc[nf] = __builtin_amdgcn_mfma_f32_16x16x32_bf16(a[s], b, acc[nf], 0, 0, 0);
            }
        }
        #pragma unroll
        for (int r = 0; r < 4; ++r) {
            size_t rowb = (size_t)(tile * 16 + kg * 4 + r) * 128;
            #pragma unroll
            for (int nf = 0; nf < 8; ++nf) {
                int col = nf * 16 + l15;
                out[rowb + col] = h[rowb + col] + acc[nf][r] + bj[nf];
            }
        }
    }
}

// ---------------------------------------------------------------------------
extern "C" void kernel_launch(void* const* d_in, const int* in_sizes, int n_in,
                              void* d_out, int out_size, void* d_ws, size_t ws_size,
                              hipStream_t stream) {
    const float* h      = (const float*)d_in[0];
    const int*   ei     = (const int*)d_in[1];
    const float* W_e1   = (const float*)d_in[2];
    const float* b_e1   = (const float*)d_in[3];
    const float* W_e2   = (const float*)d_in[4];
    const float* b_e2   = (const float*)d_in[5];
    const float* W_enc  = (const float*)d_in[6];
    const float* b_enc  = (const float*)d_in[7];
    const float* coeffs = (const float*)d_in[8];
    const float* A_real = (const float*)d_in[9];
    const float* A_imag = (const float*)d_in[10];
    const float* W_dec  = (const float*)d_in[11];
    const float* b_dec  = (const float*)d_in[12];

    float* out    = (float*)d_out;                 // N*128
    float* ef_out = out + (size_t)N_NODES * 128;   // E*128

    short* agg_bf = (short*)d_ws;                        // N*128 bf16
    short* v_bf   = agg_bf + (size_t)N_NODES * 128;      // N*128 bf16
    short* h_bf   = v_bf + (size_t)N_NODES * 128;        // N*128 bf16
    float* small  = (float*)(h_bf + (size_t)N_NODES * 128);
    float* Ybuf   = small;                 // 65536
    float* ReM    = Ybuf + 65536;          // 16384
    float* Hbuf   = ReM + 16384;           // 65536
    float* Xa     = Hbuf + 65536;          // 65536
    float* Xb     = Xa + 65536;            // 65536
    float* Tbuf   = Xb + 65536;            // 65536
    short* Dt_bf  = (short*)(Tbuf + 65536);// 16384 shorts

    hipMemsetAsync(agg_bf, 0, (size_t)N_NODES * 128 * sizeof(short), stream);

    hbf16_kernel<<<3125, 256, 0, stream>>>(h, h_bf);

    // --- D-matrix chain ---
    hmat_kernel<<<2, 1024, 0, stream>>>(A_real, A_imag, Hbuf, Xa);
    float* xc = Xa;
    float* xn = Xb;
    for (int it = 0; it < NS_ITERS; ++it) {
        ns_t_kernel<<<64, 512, 0, stream>>>(Hbuf, xc, Tbuf);
        ns_x_kernel<<<64, 512, 0, stream>>>(xc, Tbuf, xn);
        float* tmp = xc; xc = xn; xn = tmp;
    }
    gateperm_kernel<<<2, 1024, 0, stream>>>(xc, coeffs, Ybuf);
    combine1_kernel<<<32, 512, 0, stream>>>(Ybuf, ReM);
    combine2_kernel<<<32, 512, 0, stream>>>(ReM, W_dec, Dt_bf);

    edge_kernel<<<256, 1024, 0, stream>>>(h_bf, ei, W_e1, b_e1, W_e2, b_e2, ef_out, agg_bf);

    encode_kernel<<<256, 512, 0, stream>>>(h_bf, agg_bf, W_enc, b_enc, v_bf);

    decode_kernel<<<256, 512, 0, stream>>>(v_bf, h, Dt_bf, b_dec, out);
}

// Round 6
// 604.544 us; speedup vs baseline: 5.8457x; 1.0310x over previous
//
#include <hip/hip_runtime.h>
#include <math.h>

#define N_NODES 50000
#define N_EDGES 800000
#define NS_ITERS 2

typedef __attribute__((ext_vector_type(8))) short bf16x8;
typedef __attribute__((ext_vector_type(2))) short shortx2;
typedef __attribute__((ext_vector_type(4))) float f32x4;

__device__ __forceinline__ float silu_f(float x) {
    return x / (1.0f + __expf(-x));
}

__device__ __forceinline__ unsigned short f2bf(float x) {
    union { float f; unsigned u; } v; v.f = x;
    unsigned r = v.u + 0x7FFFu + ((v.u >> 16) & 1u);
    return (unsigned short)(r >> 16);
}

__device__ __forceinline__ void atomic_pk_add_bf16(short* addr, shortx2 v) {
    typedef shortx2 __attribute__((address_space(1)))* gp1;
    __builtin_amdgcn_global_atomic_fadd_v2bf16((gp1)(unsigned long long)addr, v);
}

// ---------------------------------------------------------------------------
// h (f32) -> h_bf (bf16), once. 8 elems/thread.
// ---------------------------------------------------------------------------
__global__ __launch_bounds__(256) void hbf16_kernel(const float* __restrict__ h,
                                                    short* __restrict__ hbf) {
    int i = blockIdx.x * 256 + threadIdx.x;
    const float4* h4 = (const float4*)h;
    float4 v0 = h4[i * 2], v1 = h4[i * 2 + 1];
    bf16x8 b;
    b[0] = (short)f2bf(v0.x); b[1] = (short)f2bf(v0.y);
    b[2] = (short)f2bf(v0.z); b[3] = (short)f2bf(v0.w);
    b[4] = (short)f2bf(v1.x); b[5] = (short)f2bf(v1.y);
    b[6] = (short)f2bf(v1.z); b[7] = (short)f2bf(v1.w);
    ((bf16x8*)hbf)[i] = b;
}

// ---------------------------------------------------------------------------
// H = A + A^H, X0 = H - iI  (first-order inverse of M = H + iI).
// ---------------------------------------------------------------------------
__global__ __launch_bounds__(1024) void hmat_kernel(const float* __restrict__ A_real,
                                                    const float* __restrict__ A_imag,
                                                    float* __restrict__ H,
                                                    float* __restrict__ X) {
    const int L = blockIdx.x;
    const int t = threadIdx.x;
    const float* ar = A_real + L * 16384;
    const float* ai = A_imag + L * 16384;
    float* hre = H + L * 32768;
    float* him = hre + 16384;
    float* xre = X + L * 32768;
    float* xim = xre + 16384;
    for (int q = 0; q < 16; ++q) {
        int idx = t + 1024 * q;
        int i = idx >> 7, j = idx & 127;
        float hr = ar[idx] + ar[j * 128 + i];
        float hi = ai[idx] - ai[j * 128 + i];
        hre[idx] = hr;
        him[idx] = hi;
        xre[idx] = hr;
        xim[idx] = hi - (i == j ? 1.0f : 0.0f);
    }
}

// ---------------------------------------------------------------------------
// T = M X = H X + iX.   64 blocks x 512.
// ---------------------------------------------------------------------------
__global__ __launch_bounds__(512) void ns_t_kernel(const float* __restrict__ H,
                                                   const float* __restrict__ X,
                                                   float* __restrict__ T) {
    const int L = blockIdx.x >> 5;
    const int t = threadIdx.x;
    const int i = (blockIdx.x & 31) * 4 + (t >> 7);
    const int j = t & 127;
    const float* hre = H + L * 32768;
    const float* him = hre + 16384;
    const float* xre = X + L * 32768;
    const float* xim = xre + 16384;
    float accr = 0.f, acci = 0.f;
    #pragma unroll 4
    for (int k = 0; k < 128; ++k) {
        float hr = hre[i * 128 + k], hi = him[i * 128 + k];
        float xr = xre[k * 128 + j], xi = xim[k * 128 + j];
        accr += hr * xr - hi * xi;
        acci += hr * xi + hi * xr;
    }
    T[L * 32768 + i * 128 + j]         = accr - xim[i * 128 + j];
    T[L * 32768 + 16384 + i * 128 + j] = acci + xre[i * 128 + j];
}

// ---------------------------------------------------------------------------
// Xout = 2X - X T.   64 blocks x 512.
// ---------------------------------------------------------------------------
__global__ __launch_bounds__(512) void ns_x_kernel(const float* __restrict__ X,
                                                   const float* __restrict__ T,
                                                   float* __restrict__ Xout) {
    const int L = blockIdx.x >> 5;
    const int t = threadIdx.x;
    const int i = (blockIdx.x & 31) * 4 + (t >> 7);
    const int j = t & 127;
    const float* xre = X + L * 32768;
    const float* xim = xre + 16384;
    const float* tre = T + L * 32768;
    const float* tim = tre + 16384;
    float accr = 0.f, acci = 0.f;
    #pragma unroll 4
    for (int k = 0; k < 128; ++k) {
        float xr = xre[i * 128 + k], xi = xim[i * 128 + k];
        float tr = tre[k * 128 + j], ti = tim[k * 128 + j];
        accr += xr * tr - xi * ti;
        acci += xr * ti + xi * tr;
    }
    Xout[L * 32768 + i * 128 + j]         = 2.0f * xre[i * 128 + j] - accr;
    Xout[L * 32768 + 16384 + i * 128 + j] = 2.0f * xim[i * 128 + j] - acci;
}

// ---------------------------------------------------------------------------
// Q = I - 2i*X ; G^{x7} butterflies on row index; CNOT row gather.
// ---------------------------------------------------------------------------
__global__ __launch_bounds__(1024) void gateperm_kernel(const float* __restrict__ X,
                                                        const float* __restrict__ coeffs,
                                                        float* __restrict__ Y) {
    __shared__ float Mre[128 * 129];
    __shared__ float Mim[128 * 129];
    const int L = blockIdx.x;
    const int t = threadIdx.x;
    const float* xre = X + L * 32768;
    const float* xim = xre + 16384;

    for (int q = 0; q < 16; ++q) {
        int idx = t + 1024 * q;
        int i = idx >> 7, j = idx & 127;
        Mre[i * 129 + j] = (i == j ? 1.0f : 0.0f) + 2.0f * xim[idx];
        Mim[i * 129 + j] = -2.0f * xre[idx];
    }
    __syncthreads();

    const float tx = coeffs[2 * L + 0] * 0.5f;
    const float ty = coeffs[2 * L + 1] * 0.5f;
    const float cx = cosf(tx), sx = sinf(tx), cy = cosf(ty), sy = sinf(ty);
    const float G00r = cx * cy, G00i = sx * sy;
    const float G01r = -cx * sy, G01i = -sx * cy;
    const float G10r = cx * sy, G10i = -sx * cy;
    const float G11r = cx * cy, G11i = -sx * sy;

    for (int st = 0; st < 7; ++st) {
        int b = 1 << st;
        #pragma unroll
        for (int p = 0; p < 8; ++p) {
            int pid = t + 1024 * p;
            int col = pid & 127, ph = pid >> 7;
            int i0 = ((ph >> st) << (st + 1)) | (ph & (b - 1));
            int i1 = i0 | b;
            float v0r = Mre[i0 * 129 + col], v0i = Mim[i0 * 129 + col];
            float v1r = Mre[i1 * 129 + col], v1i = Mim[i1 * 129 + col];
            Mre[i0 * 129 + col] = G00r * v0r - G00i * v0i + G01r * v1r - G01i * v1i;
            Mim[i0 * 129 + col] = G00r * v0i + G00i * v0r + G01r * v1i + G01i * v1r;
            Mre[i1 * 129 + col] = G10r * v0r - G10i * v0i + G11r * v1r - G11i * v1i;
            Mim[i1 * 129 + col] = G10r * v0i + G10i * v0r + G11r * v1i + G11i * v1r;
        }
        __syncthreads();
    }

    const int cs[7] = {6, 5, 4, 3, 2, 1, 0};
    const int ts[7] = {0, 6, 5, 4, 3, 2, 1};
    float* yre = Y + L * 32768;
    float* yim = yre + 16384;
    for (int q = 0; q < 16; ++q) {
        int idx = t + 1024 * q;
        int ii_ = idx >> 7, col = idx & 127;
        int s = ii_;
        #pragma unroll
        for (int m = 0; m < 7; ++m) {
            int cbit = 1 << (6 - cs[m]);
            int tbit = 1 << (6 - ts[m]);
            if (s & cbit) s ^= tbit;
        }
        yre[idx] = Mre[s * 129 + col];
        yim[idx] = Mim[s * 129 + col];
    }
}

// ---------------------------------------------------------------------------
// ReM = Re(Y2 * Y1). 32 blocks x 512.
// ---------------------------------------------------------------------------
__global__ __launch_bounds__(512) void combine1_kernel(const float* __restrict__ Y,
                                                       float* __restrict__ ReM) {
    __shared__ float q1r[16384];
    __shared__ float q1i[16384];
    const int t = threadIdx.x;
    const float* q1re = Y;
    const float* q1im = Y + 16384;
    const float* q2re = Y + 32768;
    const float* q2im = Y + 49152;
    for (int q = 0; q < 32; ++q) {
        q1r[t + 512 * q] = q1re[t + 512 * q];
        q1i[t + 512 * q] = q1im[t + 512 * q];
    }
    __syncthreads();
    int i = blockIdx.x * 4 + (t >> 7);
    int j = t & 127;
    float acc = 0.f;
    for (int k = 0; k < 128; ++k) {
        acc += q2re[i * 128 + k] * q1r[k * 128 + j] - q2im[i * 128 + k] * q1i[k * 128 + j];
    }
    ReM[i * 128 + j] = acc;
}

// ---------------------------------------------------------------------------
// Dt = (Re(M)^T * W_dec)^T in bf16: Dt[j][k] = sum_i ReM[i][k]*W_dec[i][j].
// ---------------------------------------------------------------------------
__global__ __launch_bounds__(512) void combine2_kernel(const float* __restrict__ ReM,
                                                       const float* __restrict__ W_dec,
                                                       short* __restrict__ Dt) {
    __shared__ float ml[16384];
    __shared__ float wl[16384];
    const int t = threadIdx.x;
    for (int q = 0; q < 32; ++q) {
        ml[t + 512 * q] = ReM[t + 512 * q];
        wl[t + 512 * q] = W_dec[t + 512 * q];
    }
    __syncthreads();
    int k = blockIdx.x * 4 + (t >> 7);
    int j = t & 127;
    float acc = 0.f;
    for (int i = 0; i < 128; ++i) {
        acc += ml[i * 128 + k] * wl[i * 128 + j];
    }
    Dt[j * 128 + k] = (short)f2bf(acc);
}

// ---------------------------------------------------------------------------
// Barrier-free edge MLP, 16 waves/block, software-pipelined h_bf gathers.
// ---------------------------------------------------------------------------
__global__ __launch_bounds__(1024, 4) void edge_kernel(const short* __restrict__ hbf,
                                                       const int* __restrict__ ei,
                                                       const float* __restrict__ W_e1,
                                                       const float* __restrict__ b_e1,
                                                       const float* __restrict__ W_e2,
                                                       const float* __restrict__ b_e2,
                                                       float* __restrict__ ef_out,
                                                       short* __restrict__ agg_bf) {
    __shared__ short w1t[128 * 256];   // 64 KiB
    __shared__ short w2t[128 * 128];   // 32 KiB
    __shared__ short c1s[16][1024];    // 32 KiB (2 KiB/wave)

    const int t = threadIdx.x;
    const int lane = t & 63;
    const int w = t >> 6;
    const int l15 = lane & 15;
    const int kg = lane >> 4;

    {
        const float4* w1_4 = (const float4*)W_e1;
        for (int q = 0; q < 8; ++q) {
            int idx4 = t + 1024 * q;
            int k = idx4 >> 5, j4 = idx4 & 31;
            float4 v = w1_4[idx4];
            int j = j4 * 4;
            w1t[(j + 0) * 256 + (k ^ (((j + 0) & 7) << 3))] = (short)f2bf(v.x);
            w1t[(j + 1) * 256 + (k ^ (((j + 1) & 7) << 3))] = (short)f2bf(v.y);
            w1t[(j + 2) * 256 + (k ^ (((j + 2) & 7) << 3))] = (short)f2bf(v.z);
            w1t[(j + 3) * 256 + (k ^ (((j + 3) & 7) << 3))] = (short)f2bf(v.w);
        }
        const float4* w2_4 = (const float4*)W_e2;
        for (int q = 0; q < 4; ++q) {
            int idx4 = t + 1024 * q;
            int k = idx4 >> 5, j4 = idx4 & 31;
            float4 v = w2_4[idx4];
            int j = j4 * 4;
            w2t[(j + 0) * 128 + (k ^ (((j + 0) & 7) << 3))] = (short)f2bf(v.x);
            w2t[(j + 1) * 128 + (k ^ (((j + 1) & 7) << 3))] = (short)f2bf(v.y);
            w2t[(j + 2) * 128 + (k ^ (((j + 2) & 7) << 3))] = (short)f2bf(v.z);
            w2t[(j + 3) * 128 + (k ^ (((j + 3) & 7) << 3))] = (short)f2bf(v.w);
        }
    }
    float b1v[8], b2v[8];
    #pragma unroll
    for (int nf = 0; nf < 8; ++nf) {
        b1v[nf] = b_e1[nf * 16 + l15];
        b2v[nf] = b_e2[nf * 16 + l15];
    }
    __syncthreads();   // only block barrier

    const bf16x8* hb8 = (const bf16x8*)hbf;
    short* myc1 = &c1s[w][0];
    const int NW = gridDim.x * 16;
    const int nt = N_EDGES / 16;

    int tile = blockIdx.x * 16 + w;
    if (tile >= nt) return;
    int ri = ei[tile * 16 + l15];
    int ci = ei[N_EDGES + tile * 16 + l15];
    bf16x8 a1[8];
    #pragma unroll
    for (int s = 0; s < 4; ++s) a1[s] = hb8[(size_t)ri * 16 + s * 4 + kg];
    #pragma unroll
    for (int s = 0; s < 4; ++s) a1[4 + s] = hb8[(size_t)ci * 16 + s * 4 + kg];
    int tn = tile + NW;
    bool more = (tn < nt);
    int rin = 0, cin = 0;
    if (more) {
        rin = ei[tn * 16 + l15];
        cin = ei[N_EDGES + tn * 16 + l15];
    }

    for (;;) {
        const int e0 = tile * 16;
        bf16x8 a1n[8];
        // prefetch next tile's row-half (covered by GEMM1+GEMM2)
        if (more) {
            #pragma unroll
            for (int s = 0; s < 4; ++s) a1n[s] = hb8[(size_t)rin * 16 + s * 4 + kg];
        }

        // ---- GEMM1: [16x256] @ [256x128] ----
        f32x4 acc[8];
        #pragma unroll
        for (int nf = 0; nf < 8; ++nf) acc[nf] = (f32x4){0.f, 0.f, 0.f, 0.f};
        #pragma unroll
        for (int s = 0; s < 8; ++s) {
            const int k0 = s * 32 + kg * 8;
            #pragma unroll
            for (int nf = 0; nf < 8; ++nf) {
                int brow = nf * 16 + l15;
                bf16x8 b = *(const bf16x8*)&w1t[brow * 256 + (k0 ^ ((brow & 7) << 3))];
                acc[nf] = __builtin_amdgcn_mfma_f32_16x16x32_bf16(a1[s], b, acc[nf], 0, 0, 0);
            }
        }

        // prefetch next tile's col-half (covered by GEMM2)
        if (more) {
            #pragma unroll
            for (int s = 0; s < 4; ++s) a1n[4 + s] = hb8[(size_t)cin * 16 + s * 4 + kg];
        }

        // ---- GEMM2 in two 64-col phases through the 2 KiB scratch ----
        f32x4 acc2[8];
        #pragma unroll
        for (int nf = 0; nf < 8; ++nf) acc2[nf] = (f32x4){0.f, 0.f, 0.f, 0.f};
        #pragma unroll
        for (int half = 0; half < 2; ++half) {
            #pragma unroll
            for (int nfh = 0; nfh < 4; ++nfh) {
                int nf = half * 4 + nfh;
                #pragma unroll
                for (int r = 0; r < 4; ++r) {
                    int row = kg * 4 + r;
                    int c = nfh * 16 + l15;
                    myc1[row * 64 + (c ^ ((row & 7) << 3))] =
                        (short)f2bf(silu_f(acc[nf][r] + b1v[nf]));
                }
            }
            #pragma unroll
            for (int s2l = 0; s2l < 2; ++s2l) {
                int k0h = s2l * 32 + kg * 8;
                bf16x8 a2 = *(const bf16x8*)&myc1[l15 * 64 + (k0h ^ ((l15 & 7) << 3))];
                int k0g = half * 64 + k0h;
                #pragma unroll
                for (int nf = 0; nf < 8; ++nf) {
                    int brow = nf * 16 + l15;
                    bf16x8 b = *(const bf16x8*)&w2t[brow * 128 + (k0g ^ ((brow & 7) << 3))];
                    acc2[nf] = __builtin_amdgcn_mfma_f32_16x16x32_bf16(a2, b, acc2[nf], 0, 0, 0);
                }
            }
        }

        // ---- output: nt stores + packed bf16 atomics ----
        int rw[4];
        #pragma unroll
        for (int r = 0; r < 4; ++r) rw[r] = __shfl(ri, kg * 4 + r);
        #pragma unroll
        for (int r = 0; r < 4; ++r) {
            int erow = kg * 4 + r;
            float* efp = ef_out + (size_t)(e0 + erow) * 128;
            short* agp = agg_bf + (size_t)rw[r] * 128;
            #pragma unroll
            for (int nf = 0; nf < 8; ++nf) {
                int col = nf * 16 + l15;
                float v = silu_f(acc2[nf][r] + b2v[nf]);
                __builtin_nontemporal_store(v, efp + col);
                float vn = __shfl_xor(v, 1);
                if ((l15 & 1) == 0) {
                    shortx2 pk;
                    pk.x = (short)f2bf(v);
                    pk.y = (short)f2bf(vn);
                    atomic_pk_add_bf16(agp + col, pk);
                }
            }
        }

        if (!more) break;
        tile = tn;
        ri = rin;
        #pragma unroll
        for (int s = 0; s < 8; ++s) a1[s] = a1n[s];
        tn = tile + NW;
        more = (tn < nt);
        if (more) {
            rin = ei[tn * 16 + l15];
            cin = ei[N_EDGES + tn * 16 + l15];
        }
    }
}

// ---------------------------------------------------------------------------
// Fused node kernel: q = [h_bf,agg_bf]@W_enc+b_enc; v=q/||q||;
// out = h + v@D + b_dec.  Per-wave 16 nodes, barrier-free after staging.
// ---------------------------------------------------------------------------
__global__ __launch_bounds__(512, 2) void node_kernel(const short* __restrict__ hbf,
                                                      const short* __restrict__ agg_bf,
                                                      const float* __restrict__ W_enc,
                                                      const float* __restrict__ b_enc,
                                                      const short* __restrict__ Dt_bf,
                                                      const float* __restrict__ b_dec,
                                                      const float* __restrict__ h,
                                                      float* __restrict__ out) {
    __shared__ short wet[128 * 256];   // 64 KiB
    __shared__ short dtl[128 * 128];   // 32 KiB
    __shared__ short c1s[8][2048];     // 32 KiB (4 KiB/wave, 16x128)

    const int t = threadIdx.x;
    const int lane = t & 63;
    const int w = t >> 6;
    const int l15 = lane & 15;
    const int kg = lane >> 4;

    {
        const float4* we4 = (const float4*)W_enc;
        for (int q = 0; q < 16; ++q) {
            int idx4 = t + 512 * q;
            int k = idx4 >> 5, j4 = idx4 & 31;
            float4 v = we4[idx4];
            int j = j4 * 4;
            wet[(j + 0) * 256 + (k ^ (((j + 0) & 7) << 3))] = (short)f2bf(v.x);
            wet[(j + 1) * 256 + (k ^ (((j + 1) & 7) << 3))] = (short)f2bf(v.y);
            wet[(j + 2) * 256 + (k ^ (((j + 2) & 7) << 3))] = (short)f2bf(v.z);
            wet[(j + 3) * 256 + (k ^ (((j + 3) & 7) << 3))] = (short)f2bf(v.w);
        }
        const int4* s4 = (const int4*)Dt_bf;
        for (int q = 0; q < 4; ++q) {
            int idx4 = t + 512 * q;
            int j = idx4 >> 4, c = idx4 & 15;
            int k0 = c * 8;
            int4 v = s4[idx4];
            *(int4*)&dtl[j * 128 + (k0 ^ ((j & 7) << 3))] = v;
        }
    }
    float bj1[8], bj2[8];
    #pragma unroll
    for (int nf = 0; nf < 8; ++nf) {
        bj1[nf] = b_enc[nf * 16 + l15];
        bj2[nf] = b_dec[nf * 16 + l15];
    }
    __syncthreads();

    const bf16x8* hb8 = (const bf16x8*)hbf;
    const bf16x8* ab8 = (const bf16x8*)agg_bf;
    short* myc1 = &c1s[w][0];
    const int NW = gridDim.x * 8;
    const int nt = N_NODES / 16;

    for (int tile = blockIdx.x * 8 + w; tile < nt; tile += NW) {
        const int node = tile * 16 + l15;
        bf16x8 a[8];
        #pragma unroll
        for (int s = 0; s < 4; ++s) a[s] = hb8[(size_t)node * 16 + s * 4 + kg];
        #pragma unroll
        for (int s = 0; s < 4; ++s) a[4 + s] = ab8[(size_t)node * 16 + s * 4 + kg];

        // ---- GEMM1: [16x256] @ W_enc [256x128] ----
        f32x4 acc[8];
        #pragma unroll
        for (int nf = 0; nf < 8; ++nf) acc[nf] = (f32x4){0.f, 0.f, 0.f, 0.f};
        #pragma unroll
        for (int s = 0; s < 8; ++s) {
            const int k0 = s * 32 + kg * 8;
            #pragma unroll
            for (int nf = 0; nf < 8; ++nf) {
                int brow = nf * 16 + l15;
                bf16x8 b = *(const bf16x8*)&wet[brow * 256 + (k0 ^ ((brow & 7) << 3))];
                acc[nf] = __builtin_amdgcn_mfma_f32_16x16x32_bf16(a[s], b, acc[nf], 0, 0, 0);
            }
        }

        // ---- bias + row-norm ----
        float nr[4] = {0.f, 0.f, 0.f, 0.f};
        #pragma unroll
        for (int nf = 0; nf < 8; ++nf) {
            #pragma unroll
            for (int r = 0; r < 4; ++r) {
                acc[nf][r] += bj1[nf];
                nr[r] += acc[nf][r] * acc[nf][r];
            }
        }
        #pragma unroll
        for (int r = 0; r < 4; ++r) {
            nr[r] += __shfl_xor(nr[r], 1);
            nr[r] += __shfl_xor(nr[r], 2);
            nr[r] += __shfl_xor(nr[r], 4);
            nr[r] += __shfl_xor(nr[r], 8);
            nr[r] = 1.0f / sqrtf(nr[r] + 1e-12f);
        }

        // ---- v (bf16) -> per-wave scratch ----
        #pragma unroll
        for (int nf = 0; nf < 8; ++nf) {
            #pragma unroll
            for (int r = 0; r < 4; ++r) {
                int row = kg * 4 + r;
                int col = nf * 16 + l15;
                myc1[row * 128 + (col ^ ((row & 7) << 3))] = (short)f2bf(acc[nf][r] * nr[r]);
            }
        }

        // ---- GEMM2: v [16x128] @ D [128x128] ----
        f32x4 acc2[8];
        #pragma unroll
        for (int nf = 0; nf < 8; ++nf) acc2[nf] = (f32x4){0.f, 0.f, 0.f, 0.f};
        #pragma unroll
        for (int s = 0; s < 4; ++s) {
            const int k0 = s * 32 + kg * 8;
            bf16x8 a2 = *(const bf16x8*)&myc1[l15 * 128 + (k0 ^ ((l15 & 7) << 3))];
            #pragma unroll
            for (int nf = 0; nf < 8; ++nf) {
                int brow = nf * 16 + l15;
                bf16x8 b = *(const bf16x8*)&dtl[brow * 128 + (k0 ^ ((brow & 7) << 3))];
                acc2[nf] = __builtin_amdgcn_mfma_f32_16x16x32_bf16(a2, b, acc2[nf], 0, 0, 0);
            }
        }

        // ---- out = h + acc2 + b_dec ----
        #pragma unroll
        for (int r = 0; r < 4; ++r) {
            size_t rowb = (size_t)(tile * 16 + kg * 4 + r) * 128;
            #pragma unroll
            for (int nf = 0; nf < 8; ++nf) {
                int col = nf * 16 + l15;
                out[rowb + col] = h[rowb + col] + acc2[nf][r] + bj2[nf];
            }
        }
    }
}

// ---------------------------------------------------------------------------
extern "C" void kernel_launch(void* const* d_in, const int* in_sizes, int n_in,
                              void* d_out, int out_size, void* d_ws, size_t ws_size,
                              hipStream_t stream) {
    const float* h      = (const float*)d_in[0];
    const int*   ei     = (const int*)d_in[1];
    const float* W_e1   = (const float*)d_in[2];
    const float* b_e1   = (const float*)d_in[3];
    const float* W_e2   = (const float*)d_in[4];
    const float* b_e2   = (const float*)d_in[5];
    const float* W_enc  = (const float*)d_in[6];
    const float* b_enc  = (const float*)d_in[7];
    const float* coeffs = (const float*)d_in[8];
    const float* A_real = (const float*)d_in[9];
    const float* A_imag = (const float*)d_in[10];
    const float* W_dec  = (const float*)d_in[11];
    const float* b_dec  = (const float*)d_in[12];

    float* out    = (float*)d_out;                 // N*128
    float* ef_out = out + (size_t)N_NODES * 128;   // E*128

    short* agg_bf = (short*)d_ws;                        // N*128 bf16
    short* h_bf   = agg_bf + (size_t)N_NODES * 128;      // N*128 bf16
    float* small  = (float*)(h_bf + (size_t)N_NODES * 128);
    float* Ybuf   = small;                 // 65536
    float* ReM    = Ybuf + 65536;          // 16384
    float* Hbuf   = ReM + 16384;           // 65536
    float* Xa     = Hbuf + 65536;          // 65536
    float* Xb     = Xa + 65536;            // 65536
    float* Tbuf   = Xb + 65536;            // 65536
    short* Dt_bf  = (short*)(Tbuf + 65536);// 16384 shorts

    hipMemsetAsync(agg_bf, 0, (size_t)N_NODES * 128 * sizeof(short), stream);

    hbf16_kernel<<<3125, 256, 0, stream>>>(h, h_bf);

    // --- D-matrix chain ---
    hmat_kernel<<<2, 1024, 0, stream>>>(A_real, A_imag, Hbuf, Xa);
    float* xc = Xa;
    float* xn = Xb;
    for (int it = 0; it < NS_ITERS; ++it) {
        ns_t_kernel<<<64, 512, 0, stream>>>(Hbuf, xc, Tbuf);
        ns_x_kernel<<<64, 512, 0, stream>>>(xc, Tbuf, xn);
        float* tmp = xc; xc = xn; xn = tmp;
    }
    gateperm_kernel<<<2, 1024, 0, stream>>>(xc, coeffs, Ybuf);
    combine1_kernel<<<32, 512, 0, stream>>>(Ybuf, ReM);
    combine2_kernel<<<32, 512, 0, stream>>>(ReM, W_dec, Dt_bf);

    edge_kernel<<<256, 1024, 0, stream>>>(h_bf, ei, W_e1, b_e1, W_e2, b_e2, ef_out, agg_bf);

    node_kernel<<<196, 512, 0, stream>>>(h_bf, agg_bf, W_enc, b_enc, Dt_bf, b_dec, h, out);
}